// Round 1
// baseline (2936.072 us; speedup 1.0000x reference)
//
#include <hip/hip_runtime.h>

#define D 1024
#define NH 16
#define HD 64
#define SEQ 2048
#define BATCH 4
#define LN_EPS 1e-5f

// ---------------------------------------------------------------------------
// LayerNorm: one block per row (8192 rows), 256 threads x float4 = 1024 elems
// ---------------------------------------------------------------------------
__global__ __launch_bounds__(256) void ln_kernel(const float* __restrict__ x,
    const float* __restrict__ gamma, const float* __restrict__ beta,
    float* __restrict__ xn)
{
    int row = blockIdx.x;
    int tid = threadIdx.x;
    float4 v = ((const float4*)(x + (size_t)row * D))[tid];
    float s = v.x + v.y + v.z + v.w;
#pragma unroll
    for (int off = 32; off > 0; off >>= 1) s += __shfl_down(s, off, 64);
    __shared__ float red1[4], red2[4];
    int wid = tid >> 6, lane = tid & 63;
    if (lane == 0) red1[wid] = s;
    __syncthreads();
    float mean = (red1[0] + red1[1] + red1[2] + red1[3]) * (1.0f / D);
    float dx = v.x - mean, dy = v.y - mean, dz = v.z - mean, dw = v.w - mean;
    float ss = dx * dx + dy * dy + dz * dz + dw * dw;
#pragma unroll
    for (int off = 32; off > 0; off >>= 1) ss += __shfl_down(ss, off, 64);
    if (lane == 0) red2[wid] = ss;
    __syncthreads();
    float var = (red2[0] + red2[1] + red2[2] + red2[3]) * (1.0f / D);
    float rstd = rsqrtf(var + LN_EPS);
    float4 g = ((const float4*)gamma)[tid];
    float4 b = ((const float4*)beta)[tid];
    float4 o;
    o.x = dx * rstd * g.x + b.x;
    o.y = dy * rstd * g.y + b.y;
    o.z = dz * rstd * g.z + b.z;
    o.w = dw * rstd * g.w + b.w;
    ((float4*)(xn + (size_t)row * D))[tid] = o;
}

// ---------------------------------------------------------------------------
// C[m,n] = sum_k A[m,k] * W[n,k] + bias[n] (+ resid[m,n])
// 64x64 tile, K-tile 16, 256 threads, 4x4 per thread.
// LDS leading dim 17: As read is broadcast across tx; Ws read is 2-way (free).
// ---------------------------------------------------------------------------
__global__ __launch_bounds__(256) void gemm_bias(const float* __restrict__ A,
    const float* __restrict__ W, const float* __restrict__ bias,
    const float* __restrict__ resid, float* __restrict__ C,
    int M, int N, int K)
{
    __shared__ float As[64][17];
    __shared__ float Ws[64][17];
    int tid = threadIdx.x;
    int tx = tid & 15, ty = tid >> 4;
    int m0 = blockIdx.y * 64, n0 = blockIdx.x * 64;
    int lr = tid >> 2;           // staging row 0..63
    int lc = (tid & 3) << 2;     // staging col 0,4,8,12
    float acc[4][4] = {};
    for (int k0 = 0; k0 < K; k0 += 16) {
        float4 a4 = *(const float4*)(A + (size_t)(m0 + lr) * K + k0 + lc);
        float4 w4 = *(const float4*)(W + (size_t)(n0 + lr) * K + k0 + lc);
        __syncthreads();  // previous tile's compute done before overwrite
        As[lr][lc] = a4.x; As[lr][lc + 1] = a4.y; As[lr][lc + 2] = a4.z; As[lr][lc + 3] = a4.w;
        Ws[lr][lc] = w4.x; Ws[lr][lc + 1] = w4.y; Ws[lr][lc + 2] = w4.z; Ws[lr][lc + 3] = w4.w;
        __syncthreads();
#pragma unroll
        for (int k = 0; k < 16; ++k) {
            float av[4], wv[4];
#pragma unroll
            for (int i = 0; i < 4; ++i) av[i] = As[ty * 4 + i][k];
#pragma unroll
            for (int j = 0; j < 4; ++j) wv[j] = Ws[tx * 4 + j][k];
#pragma unroll
            for (int i = 0; i < 4; ++i)
#pragma unroll
                for (int j = 0; j < 4; ++j)
                    acc[i][j] += av[i] * wv[j];
        }
    }
    int n = n0 + tx * 4;
    float b0 = bias[n], b1 = bias[n + 1], b2 = bias[n + 2], b3 = bias[n + 3];
#pragma unroll
    for (int i = 0; i < 4; ++i) {
        int m = m0 + ty * 4 + i;
        float4 o;
        o.x = acc[i][0] + b0;
        o.y = acc[i][1] + b1;
        o.z = acc[i][2] + b2;
        o.w = acc[i][3] + b3;
        if (resid) {
            float4 r = *(const float4*)(resid + (size_t)m * N + n);
            o.x += r.x; o.y += r.y; o.z += r.z; o.w += r.w;
        }
        *(float4*)(C + (size_t)m * N + n) = o;
    }
}

// ---------------------------------------------------------------------------
// Flash attention, causal + additive padding mask.
// Grid (S/64, NH, B); block 256 = 16x16 threads; 4x4 regs per thread.
// Q/K/V layout [B,S,D] with head h at cols h*64..h*64+63.
// ---------------------------------------------------------------------------
__global__ __launch_bounds__(256) void flash_kernel(const float* __restrict__ Q,
    const float* __restrict__ Km, const float* __restrict__ Vm,
    const float* __restrict__ mask, float* __restrict__ O)
{
    int qb = blockIdx.x, h = blockIdx.y, b = blockIdx.z;
    __shared__ float Qs[64][65];
    __shared__ float Ks[64][65];
    __shared__ float Vs[64][65];
    __shared__ float Ps[64][65];
    int tid = threadIdx.x;
    int tx = tid & 15, ty = tid >> 4;
    int lr = tid >> 2;           // staging row 0..63
    int q4 = (tid & 3) << 4;     // staging col group 0,16,32,48

    {
        const float* src = Q + ((size_t)(b * SEQ + qb * 64 + lr)) * D + h * HD + q4;
#pragma unroll
        for (int c = 0; c < 16; c += 4) {
            float4 t = *(const float4*)(src + c);
            Qs[lr][q4 + c] = t.x; Qs[lr][q4 + c + 1] = t.y;
            Qs[lr][q4 + c + 2] = t.z; Qs[lr][q4 + c + 3] = t.w;
        }
    }
    float o[4][4] = {};
    float mprev[4] = {-1e30f, -1e30f, -1e30f, -1e30f};
    float lsum[4] = {};

    for (int kb = 0; kb <= qb; ++kb) {
        __syncthreads();  // previous PV read done before restaging
        {
            const float* ksrc = Km + ((size_t)(b * SEQ + kb * 64 + lr)) * D + h * HD + q4;
            const float* vsrc = Vm + ((size_t)(b * SEQ + kb * 64 + lr)) * D + h * HD + q4;
#pragma unroll
            for (int c = 0; c < 16; c += 4) {
                float4 t = *(const float4*)(ksrc + c);
                Ks[lr][q4 + c] = t.x; Ks[lr][q4 + c + 1] = t.y;
                Ks[lr][q4 + c + 2] = t.z; Ks[lr][q4 + c + 3] = t.w;
                float4 u = *(const float4*)(vsrc + c);
                Vs[lr][q4 + c] = u.x; Vs[lr][q4 + c + 1] = u.y;
                Vs[lr][q4 + c + 2] = u.z; Vs[lr][q4 + c + 3] = u.w;
            }
        }
        __syncthreads();

        // S = Q K^T
        float s[4][4] = {};
#pragma unroll 8
        for (int d = 0; d < 64; ++d) {
            float qv[4], kv[4];
#pragma unroll
            for (int i = 0; i < 4; ++i) qv[i] = Qs[ty * 4 + i][d];
#pragma unroll
            for (int j = 0; j < 4; ++j) kv[j] = Ks[tx * 4 + j][d];
#pragma unroll
            for (int i = 0; i < 4; ++i)
#pragma unroll
                for (int j = 0; j < 4; ++j)
                    s[i][j] += qv[i] * kv[j];
        }
        // scale + padding mask + causal mask
        float padd[4];
#pragma unroll
        for (int j = 0; j < 4; ++j) {
            int kk = kb * 64 + tx * 4 + j;
            padd[j] = (1.0f - mask[b * SEQ + kk]) * -10000.0f;
        }
#pragma unroll
        for (int i = 0; i < 4; ++i) {
            int qq = qb * 64 + ty * 4 + i;
#pragma unroll
            for (int j = 0; j < 4; ++j) {
                int kk = kb * 64 + tx * 4 + j;
                float sv = s[i][j] * 0.125f + padd[j];
                s[i][j] = (kk > qq) ? -1e30f : sv;
            }
        }
        // online softmax (row spans the 16 tx lanes of this ty group)
#pragma unroll
        for (int i = 0; i < 4; ++i) {
            float rmax = fmaxf(fmaxf(s[i][0], s[i][1]), fmaxf(s[i][2], s[i][3]));
#pragma unroll
            for (int msk = 8; msk > 0; msk >>= 1)
                rmax = fmaxf(rmax, __shfl_xor(rmax, msk, 16));
            float mnew = fmaxf(mprev[i], rmax);
            float alpha = __expf(mprev[i] - mnew);
            float rsum = 0.f;
#pragma unroll
            for (int j = 0; j < 4; ++j) {
                float p = __expf(s[i][j] - mnew);
                s[i][j] = p;
                rsum += p;
            }
#pragma unroll
            for (int msk = 8; msk > 0; msk >>= 1)
                rsum += __shfl_xor(rsum, msk, 16);
            lsum[i] = lsum[i] * alpha + rsum;
            mprev[i] = mnew;
#pragma unroll
            for (int j = 0; j < 4; ++j) o[i][j] *= alpha;
#pragma unroll
            for (int j = 0; j < 4; ++j) Ps[ty * 4 + i][tx * 4 + j] = s[i][j];
        }
        __syncthreads();

        // O += P V
#pragma unroll 8
        for (int c = 0; c < 64; ++c) {
            float pv[4], vv[4];
#pragma unroll
            for (int i = 0; i < 4; ++i) pv[i] = Ps[ty * 4 + i][c];
#pragma unroll
            for (int j = 0; j < 4; ++j) vv[j] = Vs[c][tx * 4 + j];
#pragma unroll
            for (int i = 0; i < 4; ++i)
#pragma unroll
                for (int j = 0; j < 4; ++j)
                    o[i][j] += pv[i] * vv[j];
        }
    }
    // epilogue: divide by l, write [B,S,D]
#pragma unroll
    for (int i = 0; i < 4; ++i) {
        int qq = qb * 64 + ty * 4 + i;
        float inv = 1.0f / lsum[i];
        float4 ov;
        ov.x = o[i][0] * inv; ov.y = o[i][1] * inv;
        ov.z = o[i][2] * inv; ov.w = o[i][3] * inv;
        *(float4*)(O + ((size_t)(b * SEQ + qq)) * D + h * HD + tx * 4) = ov;
    }
}

// ---------------------------------------------------------------------------
extern "C" void kernel_launch(void* const* d_in, const int* in_sizes, int n_in,
                              void* d_out, int out_size, void* d_ws, size_t ws_size,
                              hipStream_t stream)
{
    const float* x     = (const float*)d_in[0];
    const float* amask = (const float*)d_in[1];
    const float* Wq    = (const float*)d_in[2];
    const float* bq    = (const float*)d_in[3];
    const float* Wk    = (const float*)d_in[4];
    const float* bk    = (const float*)d_in[5];
    const float* Wv    = (const float*)d_in[6];
    const float* bv    = (const float*)d_in[7];
    const float* Wo    = (const float*)d_in[8];
    const float* bo    = (const float*)d_in[9];
    const float* gamma = (const float*)d_in[10];
    const float* beta  = (const float*)d_in[11];
    float* out = (float*)d_out;

    const size_t MROWS = (size_t)BATCH * SEQ;  // 8192
    float* ws = (float*)d_ws;
    float* xn = ws;                       // 8M floats
    float* Qb = xn + MROWS * D;           // 8M
    float* Kb = Qb + MROWS * D;           // 8M
    float* Vb = Kb + MROWS * D;           // 8M  (total 128 MB)
    float* Ab = xn;                       // attn output reuses xn slot

    ln_kernel<<<dim3((unsigned)MROWS), 256, 0, stream>>>(x, gamma, beta, xn);

    dim3 gg(D / 64, (unsigned)(MROWS / 64));
    gemm_bias<<<gg, 256, 0, stream>>>(xn, Wq, bq, nullptr, Qb, (int)MROWS, D, D);
    gemm_bias<<<gg, 256, 0, stream>>>(xn, Wk, bk, nullptr, Kb, (int)MROWS, D, D);
    gemm_bias<<<gg, 256, 0, stream>>>(xn, Wv, bv, nullptr, Vb, (int)MROWS, D, D);

    flash_kernel<<<dim3(SEQ / 64, NH, BATCH), 256, 0, stream>>>(Qb, Kb, Vb, amask, Ab);

    gemm_bias<<<gg, 256, 0, stream>>>(Ab, Wo, bo, x, out, (int)MROWS, D, D);
}

// Round 2
// 2463.603 us; speedup vs baseline: 1.1918x; 1.1918x over previous
//
#include <hip/hip_runtime.h>

#define D 1024
#define NH 16
#define HD 64
#define SEQ 2048
#define BATCH 4
#define LN_EPS 1e-5f

typedef __attribute__((ext_vector_type(8))) __bf16 bf16x8;
typedef __attribute__((ext_vector_type(4))) float f32x4;

__device__ __forceinline__ ushort f2bf(float f) {
    union { float f; uint u; } c; c.f = f;
    uint u = c.u + 0x7fffu + ((c.u >> 16) & 1u);   // RNE
    return (ushort)(u >> 16);
}

// ---------------------------------------------------------------------------
// fp32 -> bf16 bulk convert (weights)
// ---------------------------------------------------------------------------
__global__ __launch_bounds__(256) void cvt_bf16(const float* __restrict__ in,
                                                ushort* __restrict__ out, int n)
{
    int i = (blockIdx.x * 256 + threadIdx.x) * 4;
    if (i < n) {
        float4 v = *(const float4*)(in + i);
        ushort4 o;
        o.x = f2bf(v.x); o.y = f2bf(v.y); o.z = f2bf(v.z); o.w = f2bf(v.w);
        *(ushort4*)(out + i) = o;
    }
}

// ---------------------------------------------------------------------------
// LayerNorm: one block per row, 256 threads x float4; writes bf16
// ---------------------------------------------------------------------------
__global__ __launch_bounds__(256) void ln_kernel(const float* __restrict__ x,
    const float* __restrict__ gamma, const float* __restrict__ beta,
    ushort* __restrict__ xn)
{
    int row = blockIdx.x;
    int tid = threadIdx.x;
    float4 v = ((const float4*)(x + (size_t)row * D))[tid];
    float s = v.x + v.y + v.z + v.w;
#pragma unroll
    for (int off = 32; off > 0; off >>= 1) s += __shfl_down(s, off, 64);
    __shared__ float red1[4], red2[4];
    int wid = tid >> 6, lane = tid & 63;
    if (lane == 0) red1[wid] = s;
    __syncthreads();
    float mean = (red1[0] + red1[1] + red1[2] + red1[3]) * (1.0f / D);
    float dx = v.x - mean, dy = v.y - mean, dz = v.z - mean, dw = v.w - mean;
    float ss = dx * dx + dy * dy + dz * dz + dw * dw;
#pragma unroll
    for (int off = 32; off > 0; off >>= 1) ss += __shfl_down(ss, off, 64);
    if (lane == 0) red2[wid] = ss;
    __syncthreads();
    float var = (red2[0] + red2[1] + red2[2] + red2[3]) * (1.0f / D);
    float rstd = rsqrtf(var + LN_EPS);
    float4 g = ((const float4*)gamma)[tid];
    float4 b = ((const float4*)beta)[tid];
    ushort4 o;
    o.x = f2bf(dx * rstd * g.x + b.x);
    o.y = f2bf(dy * rstd * g.y + b.y);
    o.z = f2bf(dz * rstd * g.z + b.z);
    o.w = f2bf(dw * rstd * g.w + b.w);
    ((ushort4*)(xn + (size_t)row * D))[tid] = o;
}

// ---------------------------------------------------------------------------
// bf16 MFMA GEMM: C[m,n] = sum_k A[m,k]*W[n,k] + bias[n] (+ resid), C fp32.
// 128x128 tile, BK=32, 256 threads = 4 waves (2x2), each wave 64x64 via
// 4x4 grid of 16x16x32 MFMAs. Register-staged LDS (m93 structure).
// ---------------------------------------------------------------------------
#define BM 128
#define BK 32
__global__ __launch_bounds__(256) void gemm_mfma(
    const ushort* __restrict__ A,   // [M,K] bf16
    const ushort* __restrict__ W,   // [N,K] bf16
    const float* __restrict__ bias,
    const float* __restrict__ resid,
    float* __restrict__ C,
    int M, int N, int K)
{
    __shared__ ushort As[BM * BK];
    __shared__ ushort Ws[BM * BK];
    const int tid = threadIdx.x;
    const int lane = tid & 63;
    const int wave = tid >> 6;
    const int wr = wave >> 1, wc = wave & 1;
    const int m0 = blockIdx.y * BM, n0 = blockIdx.x * BM;
    const int srow = tid >> 2;          // 0..63
    const int scol = (tid & 3) * 8;     // 0,8,16,24
    const int fr = lane & 15, quad = lane >> 4;

    f32x4 acc[4][4] = {};

    for (int k0 = 0; k0 < K; k0 += BK) {
        uint4 a0 = *(const uint4*)(A + (size_t)(m0 + srow) * K + k0 + scol);
        uint4 a1 = *(const uint4*)(A + (size_t)(m0 + 64 + srow) * K + k0 + scol);
        uint4 w0 = *(const uint4*)(W + (size_t)(n0 + srow) * K + k0 + scol);
        uint4 w1 = *(const uint4*)(W + (size_t)(n0 + 64 + srow) * K + k0 + scol);
        __syncthreads();
        *(uint4*)&As[srow * BK + scol] = a0;
        *(uint4*)&As[(64 + srow) * BK + scol] = a1;
        *(uint4*)&Ws[srow * BK + scol] = w0;
        *(uint4*)&Ws[(64 + srow) * BK + scol] = w1;
        __syncthreads();
        bf16x8 af[4], bf[4];
#pragma unroll
        for (int i = 0; i < 4; ++i) {
            af[i] = *(const bf16x8*)&As[(wr * 64 + i * 16 + fr) * BK + quad * 8];
            bf[i] = *(const bf16x8*)&Ws[(wc * 64 + i * 16 + fr) * BK + quad * 8];
        }
#pragma unroll
        for (int i = 0; i < 4; ++i)
#pragma unroll
            for (int j = 0; j < 4; ++j)
                acc[i][j] = __builtin_amdgcn_mfma_f32_16x16x32_bf16(af[i], bf[j], acc[i][j], 0, 0, 0);
    }

#pragma unroll
    for (int j = 0; j < 4; ++j) {
        int col = n0 + wc * 64 + j * 16 + fr;
        float bv = bias[col];
#pragma unroll
        for (int i = 0; i < 4; ++i) {
#pragma unroll
            for (int r = 0; r < 4; ++r) {
                int row = m0 + wr * 64 + i * 16 + quad * 4 + r;
                float v = acc[i][j][r] + bv;
                if (resid) v += resid[(size_t)row * N + col];
                C[(size_t)row * N + col] = v;
            }
        }
    }
}

// ---------------------------------------------------------------------------
// Flash attention fp32, causal + padding mask. Vectorized LDS (pad 68),
// V stored transposed for float4 PV reads. Output bf16.
// ---------------------------------------------------------------------------
__global__ __launch_bounds__(256) void flash_kernel(const float* __restrict__ Q,
    const float* __restrict__ Km, const float* __restrict__ Vm,
    const float* __restrict__ mask, ushort* __restrict__ O)
{
    int qb = blockIdx.x, h = blockIdx.y, b = blockIdx.z;
    __shared__ float Qs[64][68];
    __shared__ float Ks[64][68];
    __shared__ float Vt[64][68];   // Vt[d][seq]
    __shared__ float Ps[64][68];
    int tid = threadIdx.x;
    int tx = tid & 15, ty = tid >> 4;
    int lr = tid >> 2;           // staging row 0..63
    int q4 = (tid & 3) << 4;     // staging col group 0,16,32,48

    {
        const float* src = Q + ((size_t)(b * SEQ + qb * 64 + lr)) * D + h * HD + q4;
#pragma unroll
        for (int c = 0; c < 16; c += 4)
            *(float4*)&Qs[lr][q4 + c] = *(const float4*)(src + c);
    }
    float o[4][4] = {};
    float mprev[4] = {-1e30f, -1e30f, -1e30f, -1e30f};
    float lsum[4] = {};

    for (int kb = 0; kb <= qb; ++kb) {
        __syncthreads();  // previous iter's LDS reads done
        {
            const float* ksrc = Km + ((size_t)(b * SEQ + kb * 64 + lr)) * D + h * HD + q4;
            const float* vsrc = Vm + ((size_t)(b * SEQ + kb * 64 + lr)) * D + h * HD + q4;
#pragma unroll
            for (int c = 0; c < 16; c += 4) {
                *(float4*)&Ks[lr][q4 + c] = *(const float4*)(ksrc + c);
                float4 u = *(const float4*)(vsrc + c);
                Vt[q4 + c][lr] = u.x; Vt[q4 + c + 1][lr] = u.y;
                Vt[q4 + c + 2][lr] = u.z; Vt[q4 + c + 3][lr] = u.w;
            }
        }
        __syncthreads();

        // S = Q K^T (float4 along d)
        float s[4][4] = {};
#pragma unroll 4
        for (int d4 = 0; d4 < 64; d4 += 4) {
            float4 qv[4], kv[4];
#pragma unroll
            for (int i = 0; i < 4; ++i) qv[i] = *(const float4*)&Qs[ty * 4 + i][d4];
#pragma unroll
            for (int j = 0; j < 4; ++j) kv[j] = *(const float4*)&Ks[tx * 4 + j][d4];
#pragma unroll
            for (int i = 0; i < 4; ++i)
#pragma unroll
                for (int j = 0; j < 4; ++j)
                    s[i][j] += qv[i].x * kv[j].x + qv[i].y * kv[j].y
                             + qv[i].z * kv[j].z + qv[i].w * kv[j].w;
        }
        float padd[4];
#pragma unroll
        for (int j = 0; j < 4; ++j) {
            int kk = kb * 64 + tx * 4 + j;
            padd[j] = (1.0f - mask[b * SEQ + kk]) * -10000.0f;
        }
#pragma unroll
        for (int i = 0; i < 4; ++i) {
            int qq = qb * 64 + ty * 4 + i;
#pragma unroll
            for (int j = 0; j < 4; ++j) {
                int kk = kb * 64 + tx * 4 + j;
                float sv = s[i][j] * 0.125f + padd[j];
                s[i][j] = (kk > qq) ? -1e30f : sv;
            }
        }
#pragma unroll
        for (int i = 0; i < 4; ++i) {
            float rmax = fmaxf(fmaxf(s[i][0], s[i][1]), fmaxf(s[i][2], s[i][3]));
#pragma unroll
            for (int msk = 8; msk > 0; msk >>= 1)
                rmax = fmaxf(rmax, __shfl_xor(rmax, msk, 16));
            float mnew = fmaxf(mprev[i], rmax);
            float alpha = __expf(mprev[i] - mnew);
            float rsum = 0.f;
#pragma unroll
            for (int j = 0; j < 4; ++j) {
                float p = __expf(s[i][j] - mnew);
                s[i][j] = p;
                rsum += p;
            }
#pragma unroll
            for (int msk = 8; msk > 0; msk >>= 1)
                rsum += __shfl_xor(rsum, msk, 16);
            lsum[i] = lsum[i] * alpha + rsum;
            mprev[i] = mnew;
#pragma unroll
            for (int j = 0; j < 4; ++j) o[i][j] *= alpha;
            *(float4*)&Ps[ty * 4 + i][tx * 4] = make_float4(s[i][0], s[i][1], s[i][2], s[i][3]);
        }
        __syncthreads();

        // O += P V (float4 along c via transposed V)
#pragma unroll 4
        for (int c4 = 0; c4 < 64; c4 += 4) {
            float4 pv[4], vv[4];
#pragma unroll
            for (int i = 0; i < 4; ++i) pv[i] = *(const float4*)&Ps[ty * 4 + i][c4];
#pragma unroll
            for (int j = 0; j < 4; ++j) vv[j] = *(const float4*)&Vt[tx * 4 + j][c4];
#pragma unroll
            for (int i = 0; i < 4; ++i)
#pragma unroll
                for (int j = 0; j < 4; ++j)
                    o[i][j] += pv[i].x * vv[j].x + pv[i].y * vv[j].y
                             + pv[i].z * vv[j].z + pv[i].w * vv[j].w;
        }
    }
#pragma unroll
    for (int i = 0; i < 4; ++i) {
        int qq = qb * 64 + ty * 4 + i;
        float inv = 1.0f / lsum[i];
        ushort4 ov;
        ov.x = f2bf(o[i][0] * inv); ov.y = f2bf(o[i][1] * inv);
        ov.z = f2bf(o[i][2] * inv); ov.w = f2bf(o[i][3] * inv);
        *(ushort4*)(O + ((size_t)(b * SEQ + qq)) * D + h * HD + tx * 4) = ov;
    }
}

// ---------------------------------------------------------------------------
extern "C" void kernel_launch(void* const* d_in, const int* in_sizes, int n_in,
                              void* d_out, int out_size, void* d_ws, size_t ws_size,
                              hipStream_t stream)
{
    const float* x     = (const float*)d_in[0];
    const float* amask = (const float*)d_in[1];
    const float* Wq    = (const float*)d_in[2];
    const float* bq    = (const float*)d_in[3];
    const float* Wk    = (const float*)d_in[4];
    const float* bk    = (const float*)d_in[5];
    const float* Wv    = (const float*)d_in[6];
    const float* bv    = (const float*)d_in[7];
    const float* Wo    = (const float*)d_in[8];
    const float* bo    = (const float*)d_in[9];
    const float* gamma = (const float*)d_in[10];
    const float* beta  = (const float*)d_in[11];
    float* out = (float*)d_out;

    const size_t MROWS = (size_t)BATCH * SEQ;  // 8192
    char* ws = (char*)d_ws;
    float*  Qb    = (float*)(ws);                          // 32 MB
    float*  Kb    = (float*)(ws + (size_t)32  * 1024 * 1024); // 32 MB
    float*  Vb    = (float*)(ws + (size_t)64  * 1024 * 1024); // 32 MB
    ushort* xn_bf = (ushort*)(ws + (size_t)96 * 1024 * 1024); // 16 MB (reused as attn_bf)
    ushort* Wq_bf = (ushort*)(ws + (size_t)112 * 1024 * 1024);
    ushort* Wk_bf = (ushort*)(ws + (size_t)114 * 1024 * 1024);
    ushort* Wv_bf = (ushort*)(ws + (size_t)116 * 1024 * 1024);
    ushort* Wo_bf = (ushort*)(ws + (size_t)118 * 1024 * 1024);
    ushort* attn_bf = xn_bf;

    const int WN = D * D;  // 1M elements per weight
    cvt_bf16<<<WN / 1024, 256, 0, stream>>>(Wq, Wq_bf, WN);
    cvt_bf16<<<WN / 1024, 256, 0, stream>>>(Wk, Wk_bf, WN);
    cvt_bf16<<<WN / 1024, 256, 0, stream>>>(Wv, Wv_bf, WN);
    cvt_bf16<<<WN / 1024, 256, 0, stream>>>(Wo, Wo_bf, WN);

    ln_kernel<<<dim3((unsigned)MROWS), 256, 0, stream>>>(x, gamma, beta, xn_bf);

    dim3 gg(D / 128, (unsigned)(MROWS / 128));
    gemm_mfma<<<gg, 256, 0, stream>>>(xn_bf, Wq_bf, bq, nullptr, Qb, (int)MROWS, D, D);
    gemm_mfma<<<gg, 256, 0, stream>>>(xn_bf, Wk_bf, bk, nullptr, Kb, (int)MROWS, D, D);
    gemm_mfma<<<gg, 256, 0, stream>>>(xn_bf, Wv_bf, bv, nullptr, Vb, (int)MROWS, D, D);

    flash_kernel<<<dim3(SEQ / 64, NH, BATCH), 256, 0, stream>>>(Qb, Kb, Vb, amask, attn_bf);

    gemm_mfma<<<gg, 256, 0, stream>>>(attn_bf, Wo_bf, bo, x, out, (int)MROWS, D, D);
}

// Round 3
// 539.552 us; speedup vs baseline: 5.4417x; 4.5660x over previous
//
#include <hip/hip_runtime.h>

#define D 1024
#define NH 16
#define HD 64
#define SEQ 2048
#define BATCH 4
#define LN_EPS 1e-5f

typedef __attribute__((ext_vector_type(8))) __bf16 bf16x8;
typedef __attribute__((ext_vector_type(4))) float f32x4;

__device__ __forceinline__ ushort f2bf(float f) {
    union { float f; uint u; } c; c.f = f;
    uint u = c.u + 0x7fffu + ((c.u >> 16) & 1u);   // RNE
    return (ushort)(u >> 16);
}

// ---------------------------------------------------------------------------
// fp32 -> bf16 bulk convert (weights)
// ---------------------------------------------------------------------------
__global__ __launch_bounds__(256) void cvt_bf16(const float* __restrict__ in,
                                                ushort* __restrict__ out, int n)
{
    int i = (blockIdx.x * 256 + threadIdx.x) * 4;
    if (i < n) {
        float4 v = *(const float4*)(in + i);
        ushort4 o;
        o.x = f2bf(v.x); o.y = f2bf(v.y); o.z = f2bf(v.z); o.w = f2bf(v.w);
        *(ushort4*)(out + i) = o;
    }
}

// ---------------------------------------------------------------------------
// LayerNorm: one block per row, 256 threads x float4; writes bf16
// ---------------------------------------------------------------------------
__global__ __launch_bounds__(256) void ln_kernel(const float* __restrict__ x,
    const float* __restrict__ gamma, const float* __restrict__ beta,
    ushort* __restrict__ xn)
{
    int row = blockIdx.x;
    int tid = threadIdx.x;
    float4 v = ((const float4*)(x + (size_t)row * D))[tid];
    float s = v.x + v.y + v.z + v.w;
#pragma unroll
    for (int off = 32; off > 0; off >>= 1) s += __shfl_down(s, off, 64);
    __shared__ float red1[4], red2[4];
    int wid = tid >> 6, lane = tid & 63;
    if (lane == 0) red1[wid] = s;
    __syncthreads();
    float mean = (red1[0] + red1[1] + red1[2] + red1[3]) * (1.0f / D);
    float dx = v.x - mean, dy = v.y - mean, dz = v.z - mean, dw = v.w - mean;
    float ss = dx * dx + dy * dy + dz * dz + dw * dw;
#pragma unroll
    for (int off = 32; off > 0; off >>= 1) ss += __shfl_down(ss, off, 64);
    if (lane == 0) red2[wid] = ss;
    __syncthreads();
    float var = (red2[0] + red2[1] + red2[2] + red2[3]) * (1.0f / D);
    float rstd = rsqrtf(var + LN_EPS);
    float4 g = ((const float4*)gamma)[tid];
    float4 b = ((const float4*)beta)[tid];
    ushort4 o;
    o.x = f2bf(dx * rstd * g.x + b.x);
    o.y = f2bf(dy * rstd * g.y + b.y);
    o.z = f2bf(dz * rstd * g.z + b.z);
    o.w = f2bf(dw * rstd * g.w + b.w);
    ((ushort4*)(xn + (size_t)row * D))[tid] = o;
}

// ---------------------------------------------------------------------------
// bf16 MFMA GEMM: C[m,n] = sum_k A[m,k]*W[n,k] + bias[n] (+ resid).
// Output fp32 (Cf, with optional resid) or bf16 (Cb) per write_bf16 flag.
// 128x128 tile, BK=32, 256 threads = 4 waves (2x2).
// ---------------------------------------------------------------------------
#define BM 128
#define BK 32
__global__ __launch_bounds__(256) void gemm_mfma(
    const ushort* __restrict__ A,   // [M,K] bf16
    const ushort* __restrict__ W,   // [N,K] bf16
    const float* __restrict__ bias,
    const float* __restrict__ resid,
    float* __restrict__ Cf,
    ushort* __restrict__ Cb,
    int write_bf16,
    int M, int N, int K)
{
    __shared__ ushort As[BM * BK];
    __shared__ ushort Ws[BM * BK];
    const int tid = threadIdx.x;
    const int lane = tid & 63;
    const int wave = tid >> 6;
    const int wr = wave >> 1, wc = wave & 1;
    const int m0 = blockIdx.y * BM, n0 = blockIdx.x * BM;
    const int srow = tid >> 2;          // 0..63
    const int scol = (tid & 3) * 8;     // 0,8,16,24
    const int fr = lane & 15, quad = lane >> 4;

    f32x4 acc[4][4] = {};

    for (int k0 = 0; k0 < K; k0 += BK) {
        uint4 a0 = *(const uint4*)(A + (size_t)(m0 + srow) * K + k0 + scol);
        uint4 a1 = *(const uint4*)(A + (size_t)(m0 + 64 + srow) * K + k0 + scol);
        uint4 w0 = *(const uint4*)(W + (size_t)(n0 + srow) * K + k0 + scol);
        uint4 w1 = *(const uint4*)(W + (size_t)(n0 + 64 + srow) * K + k0 + scol);
        __syncthreads();
        *(uint4*)&As[srow * BK + scol] = a0;
        *(uint4*)&As[(64 + srow) * BK + scol] = a1;
        *(uint4*)&Ws[srow * BK + scol] = w0;
        *(uint4*)&Ws[(64 + srow) * BK + scol] = w1;
        __syncthreads();
        bf16x8 af[4], bf[4];
#pragma unroll
        for (int i = 0; i < 4; ++i) {
            af[i] = *(const bf16x8*)&As[(wr * 64 + i * 16 + fr) * BK + quad * 8];
            bf[i] = *(const bf16x8*)&Ws[(wc * 64 + i * 16 + fr) * BK + quad * 8];
        }
#pragma unroll
        for (int i = 0; i < 4; ++i)
#pragma unroll
            for (int j = 0; j < 4; ++j)
                acc[i][j] = __builtin_amdgcn_mfma_f32_16x16x32_bf16(af[i], bf[j], acc[i][j], 0, 0, 0);
    }

#pragma unroll
    for (int j = 0; j < 4; ++j) {
        int col = n0 + wc * 64 + j * 16 + fr;
        float bv = bias[col];
#pragma unroll
        for (int i = 0; i < 4; ++i) {
#pragma unroll
            for (int r = 0; r < 4; ++r) {
                int row = m0 + wr * 64 + i * 16 + quad * 4 + r;
                float v = acc[i][j][r] + bv;
                if (write_bf16) {
                    Cb[(size_t)row * N + col] = f2bf(v);
                } else {
                    if (resid) v += resid[(size_t)row * N + col];
                    Cf[(size_t)row * N + col] = v;
                }
            }
        }
    }
}

// ---------------------------------------------------------------------------
// MFMA flash attention, bf16 inputs/outputs, fp32 softmax state.
// Grid (S/64, NH, B); 256 threads = 4 waves, each owns a 16-row q strip.
// ---------------------------------------------------------------------------
#define LDP 72   // LDS row pitch in bf16 (64 + 8, keeps 16B alignment)
__global__ __launch_bounds__(256) void flash_mfma(
    const ushort* __restrict__ Q, const ushort* __restrict__ K,
    const ushort* __restrict__ V, const float* __restrict__ mask,
    ushort* __restrict__ O)
{
    const int qb = blockIdx.x, h = blockIdx.y, b = blockIdx.z;
    __shared__ ushort Qs[64 * LDP];
    __shared__ ushort Ks[64 * LDP];
    __shared__ ushort Vt[64 * LDP];   // Vt[d][key]
    __shared__ ushort Ps[64 * LDP];   // wave-private 16-row strips
    const int tid = threadIdx.x;
    const int lane = tid & 63, wave = tid >> 6;
    const int fr = lane & 15, quad = lane >> 4;
    const int srow = tid >> 3;           // 0..31
    const int scol = (tid & 7) * 8;      // 0..56
    const int vd = tid & 63;             // d for V transpose staging
    const int vk0 = (tid >> 6) * 8;      // key group 0,8,16,24

    const size_t baseQ = ((size_t)(b * SEQ + qb * 64)) * D + h * HD;
    *(uint4*)&Qs[srow * LDP + scol] =
        *(const uint4*)(Q + baseQ + (size_t)srow * D + scol);
    *(uint4*)&Qs[(srow + 32) * LDP + scol] =
        *(const uint4*)(Q + baseQ + (size_t)(srow + 32) * D + scol);

    f32x4 o[4] = {};                      // o[j][r]: d=j*16+fr, row=quad*4+r
    float mprev[4] = {-1e30f, -1e30f, -1e30f, -1e30f};
    float lsum[4] = {};

    for (int kb = 0; kb <= qb; ++kb) {
        const size_t baseK = ((size_t)(b * SEQ + kb * 64)) * D + h * HD;
        __syncthreads();   // prev iter's Ks/Vt reads done (also Qs visible, iter 0)
        *(uint4*)&Ks[srow * LDP + scol] =
            *(const uint4*)(K + baseK + (size_t)srow * D + scol);
        *(uint4*)&Ks[(srow + 32) * LDP + scol] =
            *(const uint4*)(K + baseK + (size_t)(srow + 32) * D + scol);
#pragma unroll
        for (int half = 0; half < 2; ++half) {
            int k0 = half * 32 + vk0;
            ushort tmp[8] __attribute__((aligned(16)));
#pragma unroll
            for (int t = 0; t < 8; ++t)
                tmp[t] = V[baseK + (size_t)(k0 + t) * D + vd];
            *(uint4*)&Vt[vd * LDP + k0] = *(const uint4*)tmp;
        }
        __syncthreads();

        // ---- S = Q K^T (wave strip: rows wave*16..+15, keys 0..63) ----
        f32x4 sacc[4] = {};
        bf16x8 aq0 = *(const bf16x8*)&Qs[(wave * 16 + fr) * LDP + quad * 8];
        bf16x8 aq1 = *(const bf16x8*)&Qs[(wave * 16 + fr) * LDP + 32 + quad * 8];
#pragma unroll
        for (int j = 0; j < 4; ++j) {
            bf16x8 bk0 = *(const bf16x8*)&Ks[(j * 16 + fr) * LDP + quad * 8];
            bf16x8 bk1 = *(const bf16x8*)&Ks[(j * 16 + fr) * LDP + 32 + quad * 8];
            sacc[j] = __builtin_amdgcn_mfma_f32_16x16x32_bf16(aq0, bk0, sacc[j], 0, 0, 0);
            sacc[j] = __builtin_amdgcn_mfma_f32_16x16x32_bf16(aq1, bk1, sacc[j], 0, 0, 0);
        }

        // ---- mask + online softmax ----
        float padd[4];
#pragma unroll
        for (int j = 0; j < 4; ++j)
            padd[j] = (1.0f - mask[b * SEQ + kb * 64 + j * 16 + fr]) * -10000.0f;
#pragma unroll
        for (int r = 0; r < 4; ++r) {
            int qq = qb * 64 + wave * 16 + quad * 4 + r;
            float v[4];
            float rmax = -1e30f;
#pragma unroll
            for (int j = 0; j < 4; ++j) {
                int kk = kb * 64 + j * 16 + fr;
                float sv = sacc[j][r] * 0.125f + padd[j];
                v[j] = (kk > qq) ? -1e30f : sv;
                rmax = fmaxf(rmax, v[j]);
            }
#pragma unroll
            for (int m = 8; m; m >>= 1) rmax = fmaxf(rmax, __shfl_xor(rmax, m, 16));
            float mnew = fmaxf(mprev[r], rmax);
            float alpha = __expf(mprev[r] - mnew);
            float rsum = 0.f;
            ushort pb[4];
#pragma unroll
            for (int j = 0; j < 4; ++j) {
                float p = __expf(v[j] - mnew);
                rsum += p;
                pb[j] = f2bf(p);
            }
#pragma unroll
            for (int m = 8; m; m >>= 1) rsum += __shfl_xor(rsum, m, 16);
            lsum[r] = lsum[r] * alpha + rsum;
            mprev[r] = mnew;
#pragma unroll
            for (int j = 0; j < 4; ++j) {
                o[j][r] *= alpha;
                Ps[(wave * 16 + quad * 4 + r) * LDP + j * 16 + fr] = pb[j];
            }
        }
        // Ps strip is wave-private: no barrier needed before re-reading it.

        // ---- O += P V ----
        bf16x8 pa0 = *(const bf16x8*)&Ps[(wave * 16 + fr) * LDP + quad * 8];
        bf16x8 pa1 = *(const bf16x8*)&Ps[(wave * 16 + fr) * LDP + 32 + quad * 8];
#pragma unroll
        for (int j = 0; j < 4; ++j) {
            bf16x8 bv0 = *(const bf16x8*)&Vt[(j * 16 + fr) * LDP + quad * 8];
            bf16x8 bv1 = *(const bf16x8*)&Vt[(j * 16 + fr) * LDP + 32 + quad * 8];
            o[j] = __builtin_amdgcn_mfma_f32_16x16x32_bf16(pa0, bv0, o[j], 0, 0, 0);
            o[j] = __builtin_amdgcn_mfma_f32_16x16x32_bf16(pa1, bv1, o[j], 0, 0, 0);
        }
    }

    // ---- epilogue: O / l, write bf16 [B,S,D] ----
#pragma unroll
    for (int r = 0; r < 4; ++r) {
        int qq = qb * 64 + wave * 16 + quad * 4 + r;
        float inv = 1.0f / lsum[r];
#pragma unroll
        for (int j = 0; j < 4; ++j)
            O[((size_t)(b * SEQ + qq)) * D + h * HD + j * 16 + fr] = f2bf(o[j][r] * inv);
    }
}

// ---------------------------------------------------------------------------
extern "C" void kernel_launch(void* const* d_in, const int* in_sizes, int n_in,
                              void* d_out, int out_size, void* d_ws, size_t ws_size,
                              hipStream_t stream)
{
    const float* x     = (const float*)d_in[0];
    const float* amask = (const float*)d_in[1];
    const float* Wq    = (const float*)d_in[2];
    const float* bq    = (const float*)d_in[3];
    const float* Wk    = (const float*)d_in[4];
    const float* bk    = (const float*)d_in[5];
    const float* Wv    = (const float*)d_in[6];
    const float* bv    = (const float*)d_in[7];
    const float* Wo    = (const float*)d_in[8];
    const float* bo    = (const float*)d_in[9];
    const float* gamma = (const float*)d_in[10];
    const float* beta  = (const float*)d_in[11];
    float* out = (float*)d_out;

    const size_t MROWS = (size_t)BATCH * SEQ;  // 8192
    const size_t MB = 1024 * 1024;
    char* ws = (char*)d_ws;
    ushort* Qb    = (ushort*)(ws);             // 16 MB bf16
    ushort* Kb    = (ushort*)(ws + 16 * MB);   // 16 MB
    ushort* Vb    = (ushort*)(ws + 32 * MB);   // 16 MB
    ushort* xn_bf = (ushort*)(ws + 48 * MB);   // 16 MB (reused as attn_bf)
    ushort* Wq_bf = (ushort*)(ws + 64 * MB);   // 2 MB each
    ushort* Wk_bf = (ushort*)(ws + 66 * MB);
    ushort* Wv_bf = (ushort*)(ws + 68 * MB);
    ushort* Wo_bf = (ushort*)(ws + 70 * MB);
    ushort* attn_bf = xn_bf;

    const int WN = D * D;
    cvt_bf16<<<WN / 1024, 256, 0, stream>>>(Wq, Wq_bf, WN);
    cvt_bf16<<<WN / 1024, 256, 0, stream>>>(Wk, Wk_bf, WN);
    cvt_bf16<<<WN / 1024, 256, 0, stream>>>(Wv, Wv_bf, WN);
    cvt_bf16<<<WN / 1024, 256, 0, stream>>>(Wo, Wo_bf, WN);

    ln_kernel<<<dim3((unsigned)MROWS), 256, 0, stream>>>(x, gamma, beta, xn_bf);

    dim3 gg(D / 128, (unsigned)(MROWS / 128));
    gemm_mfma<<<gg, 256, 0, stream>>>(xn_bf, Wq_bf, bq, nullptr, nullptr, Qb, 1, (int)MROWS, D, D);
    gemm_mfma<<<gg, 256, 0, stream>>>(xn_bf, Wk_bf, bk, nullptr, nullptr, Kb, 1, (int)MROWS, D, D);
    gemm_mfma<<<gg, 256, 0, stream>>>(xn_bf, Wv_bf, bv, nullptr, nullptr, Vb, 1, (int)MROWS, D, D);

    flash_mfma<<<dim3(SEQ / 64, NH, BATCH), 256, 0, stream>>>(Qb, Kb, Vb, amask, attn_bf);

    gemm_mfma<<<gg, 256, 0, stream>>>(attn_bf, Wo_bf, bo, x, out, nullptr, 0, (int)MROWS, D, D);
}

// Round 4
// 507.936 us; speedup vs baseline: 5.7804x; 1.0622x over previous
//
#include <hip/hip_runtime.h>

#define D 1024
#define NH 16
#define HD 64
#define SEQ 2048
#define BATCH 4
#define LN_EPS 1e-5f
#define LOG2E 1.44269504088896f

typedef __attribute__((ext_vector_type(8))) __bf16 bf16x8;
typedef __attribute__((ext_vector_type(4))) float f32x4;

__device__ __forceinline__ ushort f2bf(float f) {
    union { float f; uint u; } c; c.f = f;
    uint u = c.u + 0x7fffu + ((c.u >> 16) & 1u);   // RNE
    return (ushort)(u >> 16);
}

// async global->LDS DMA, 16B per lane; LDS dest = wave-uniform base + lane*16
__device__ __forceinline__ void gl_lds16(const ushort* g, ushort* lds) {
    __builtin_amdgcn_global_load_lds(
        (const __attribute__((address_space(1))) void*)g,
        (__attribute__((address_space(3))) void*)lds, 16, 0, 0);
}

// ---------------------------------------------------------------------------
// fp32 -> bf16 bulk convert (weights)
// ---------------------------------------------------------------------------
__global__ __launch_bounds__(256) void cvt_bf16(const float* __restrict__ in,
                                                ushort* __restrict__ out, int n)
{
    int i = (blockIdx.x * 256 + threadIdx.x) * 4;
    if (i < n) {
        float4 v = *(const float4*)(in + i);
        ushort4 o;
        o.x = f2bf(v.x); o.y = f2bf(v.y); o.z = f2bf(v.z); o.w = f2bf(v.w);
        *(ushort4*)(out + i) = o;
    }
}

// ---------------------------------------------------------------------------
// LayerNorm: one block per row, 256 threads x float4; writes bf16
// ---------------------------------------------------------------------------
__global__ __launch_bounds__(256) void ln_kernel(const float* __restrict__ x,
    const float* __restrict__ gamma, const float* __restrict__ beta,
    ushort* __restrict__ xn)
{
    int row = blockIdx.x;
    int tid = threadIdx.x;
    float4 v = ((const float4*)(x + (size_t)row * D))[tid];
    float s = v.x + v.y + v.z + v.w;
#pragma unroll
    for (int off = 32; off > 0; off >>= 1) s += __shfl_down(s, off, 64);
    __shared__ float red1[4], red2[4];
    int wid = tid >> 6, lane = tid & 63;
    if (lane == 0) red1[wid] = s;
    __syncthreads();
    float mean = (red1[0] + red1[1] + red1[2] + red1[3]) * (1.0f / D);
    float dx = v.x - mean, dy = v.y - mean, dz = v.z - mean, dw = v.w - mean;
    float ss = dx * dx + dy * dy + dz * dz + dw * dw;
#pragma unroll
    for (int off = 32; off > 0; off >>= 1) ss += __shfl_down(ss, off, 64);
    if (lane == 0) red2[wid] = ss;
    __syncthreads();
    float var = (red2[0] + red2[1] + red2[2] + red2[3]) * (1.0f / D);
    float rstd = rsqrtf(var + LN_EPS);
    float4 g = ((const float4*)gamma)[tid];
    float4 b = ((const float4*)beta)[tid];
    ushort4 o;
    o.x = f2bf(dx * rstd * g.x + b.x);
    o.y = f2bf(dy * rstd * g.y + b.y);
    o.z = f2bf(dz * rstd * g.z + b.z);
    o.w = f2bf(dw * rstd * g.w + b.w);
    ((ushort4*)(xn + (size_t)row * D))[tid] = o;
}

// ---------------------------------------------------------------------------
// bf16 MFMA GEMM, m97 structure: global_load_lds width-16 staging.
// 128x128 tile, BK=32, 256 threads = 4 waves (2x2).
// ---------------------------------------------------------------------------
#define BM 128
#define BK 32
__global__ __launch_bounds__(256) void gemm_mfma(
    const ushort* __restrict__ A,   // [M,K] bf16
    const ushort* __restrict__ W,   // [N,K] bf16
    const float* __restrict__ bias,
    const float* __restrict__ resid,
    float* __restrict__ Cf,
    ushort* __restrict__ Cb,
    int write_bf16,
    int M, int N, int K)
{
    __shared__ ushort As[BM * BK];   // 8 KB, lane-contiguous: slot = tid*16B
    __shared__ ushort Ws[BM * BK];
    const int tid = threadIdx.x;
    const int lane = tid & 63;
    const int wave = tid >> 6;
    const int wr = wave >> 1, wc = wave & 1;
    const int m0 = blockIdx.y * BM, n0 = blockIdx.x * BM;
    const int srow = tid >> 2;          // 0..63
    const int scol = (tid & 3) * 8;     // 0,8,16,24
    const int fr = lane & 15, quad = lane >> 4;

    const ushort* gA0 = A + (size_t)(m0 + srow) * K + scol;
    const ushort* gA1 = gA0 + (size_t)64 * K;
    const ushort* gW0 = W + (size_t)(n0 + srow) * K + scol;
    const ushort* gW1 = gW0 + (size_t)64 * K;

    f32x4 acc[4][4] = {};

    for (int k0 = 0; k0 < K; k0 += BK) {
        __syncthreads();                       // prev iter's LDS reads done
        gl_lds16(gA0 + k0, As + wave * 512);
        gl_lds16(gA1 + k0, As + 2048 + wave * 512);
        gl_lds16(gW0 + k0, Ws + wave * 512);
        gl_lds16(gW1 + k0, Ws + 2048 + wave * 512);
        __syncthreads();                       // vmcnt drain + barrier
        bf16x8 af[4], bf[4];
#pragma unroll
        for (int i = 0; i < 4; ++i) {
            af[i] = *(const bf16x8*)&As[(wr * 64 + i * 16 + fr) * BK + quad * 8];
            bf[i] = *(const bf16x8*)&Ws[(wc * 64 + i * 16 + fr) * BK + quad * 8];
        }
#pragma unroll
        for (int i = 0; i < 4; ++i)
#pragma unroll
            for (int j = 0; j < 4; ++j)
                acc[i][j] = __builtin_amdgcn_mfma_f32_16x16x32_bf16(af[i], bf[j], acc[i][j], 0, 0, 0);
    }

#pragma unroll
    for (int j = 0; j < 4; ++j) {
        int col = n0 + wc * 64 + j * 16 + fr;
        float bv = bias[col];
#pragma unroll
        for (int i = 0; i < 4; ++i) {
#pragma unroll
            for (int r = 0; r < 4; ++r) {
                int row = m0 + wr * 64 + i * 16 + quad * 4 + r;
                float v = acc[i][j][r] + bv;
                if (write_bf16) {
                    Cb[(size_t)row * N + col] = f2bf(v);
                } else {
                    if (resid) v += resid[(size_t)row * N + col];
                    Cf[(size_t)row * N + col] = v;
                }
            }
        }
    }
}

// ---------------------------------------------------------------------------
// V transpose: [B,S,D] bf16 -> Vt[b][h][d][s]  (both sides coalesced via LDS)
// ---------------------------------------------------------------------------
__global__ __launch_bounds__(256) void vtrans(const ushort* __restrict__ V,
                                              ushort* __restrict__ VtG)
{
    int sb = blockIdx.x, h = blockIdx.y, b = blockIdx.z;
    __shared__ ushort Ts[64 * 72];
    int t = threadIdx.x;
    int r = t >> 3, c8 = (t & 7) * 8;
    const ushort* src = V + ((size_t)(b * SEQ + sb * 64)) * D + h * HD;
    *(uint4*)&Ts[r * 72 + c8] = *(const uint4*)(src + (size_t)r * D + c8);
    *(uint4*)&Ts[(r + 32) * 72 + c8] = *(const uint4*)(src + (size_t)(r + 32) * D + c8);
    __syncthreads();
    ushort* dst = VtG + ((size_t)(b * NH + h) * HD) * SEQ + sb * 64;
#pragma unroll
    for (int half = 0; half < 2; ++half) {
        int d = r + half * 32;
        ushort tmp[8] __attribute__((aligned(16)));
#pragma unroll
        for (int k = 0; k < 8; ++k) tmp[k] = Ts[(c8 + k) * 72 + d];
        *(uint4*)(dst + (size_t)d * SEQ + c8) = *(const uint4*)tmp;
    }
}

// ---------------------------------------------------------------------------
// MFMA flash attention. Q/K bf16 [B,S,D]; V pre-transposed Vt[b][h][d][s].
// K/Vt staged via global_load_lds with XOR-swizzled columns (pitch 64, no pad,
// conflict-free b128 reads). Q frags hoisted. exp2-domain softmax.
// ---------------------------------------------------------------------------
#define LQP 72
__global__ __launch_bounds__(256) void flash_mfma(
    const ushort* __restrict__ Q, const ushort* __restrict__ K,
    const ushort* __restrict__ VtG, const float* __restrict__ mask,
    ushort* __restrict__ O)
{
    const int qb = (int)(gridDim.x - 1) - (int)blockIdx.x;   // heavy blocks first
    const int h = blockIdx.y, b = blockIdx.z;
    __shared__ ushort Qs[64 * LQP];
    __shared__ ushort Ks[64 * 64];   // lane-contiguous DMA layout, swizzled cols
    __shared__ ushort Vt[64 * 64];
    __shared__ ushort Ps[64 * LQP];  // wave-private strips
    const int tid = threadIdx.x;
    const int lane = tid & 63, wave = tid >> 6;
    const int fr = lane & 15, quad = lane >> 4;
    const int srow = tid >> 3;                    // 0..31
    const int sc8 = tid & 7;                      // LDS col group
    const int g8 = sc8 ^ (srow & 7);              // swizzled global col group

    // ---- stage Q once (pitch 72, unswizzled), hoist fragments ----
    const size_t baseQ = ((size_t)(b * SEQ + qb * 64)) * D + h * HD;
    *(uint4*)&Qs[srow * LQP + sc8 * 8] =
        *(const uint4*)(Q + baseQ + (size_t)srow * D + sc8 * 8);
    *(uint4*)&Qs[(srow + 32) * LQP + sc8 * 8] =
        *(const uint4*)(Q + baseQ + (size_t)(srow + 32) * D + sc8 * 8);
    __syncthreads();
    bf16x8 aq0 = *(const bf16x8*)&Qs[(wave * 16 + fr) * LQP + quad * 8];
    bf16x8 aq1 = *(const bf16x8*)&Qs[(wave * 16 + fr) * LQP + 32 + quad * 8];

    // staging pointers (advance by kb)
    const ushort* gK0 = K + (size_t)(b * SEQ) * D + h * HD + (size_t)srow * D + g8 * 8;
    const ushort* gK1 = gK0 + (size_t)32 * D;
    const ushort* gV0 = VtG + ((size_t)(b * NH + h) * HD) * SEQ + (size_t)srow * SEQ + g8 * 8;
    const ushort* gV1 = gV0 + (size_t)32 * SEQ;
    const float* mrow = mask + (size_t)b * SEQ;

    // fragment-read swizzled column offsets (row&7 == fr&7 for row = j*16+fr)
    const int swf = fr & 7;
    const int off0 = ((quad) ^ swf) * 8;        // keys/d 0..31 half
    const int off1 = ((4 + quad) ^ swf) * 8;    // keys/d 32..63 half

    f32x4 o[4] = {};                      // o[j][r]: d=j*16+fr, q-row=quad*4+r
    float mprev[4] = {-1e30f, -1e30f, -1e30f, -1e30f};
    float lsum[4] = {};
    const float SCALE2 = 0.125f * LOG2E;

    for (int kb = 0; kb <= qb; ++kb) {
        __syncthreads();                               // prev iter reads done
        const size_t koff = (size_t)kb * 64 * D;
        gl_lds16(gK0 + koff, Ks + wave * 512);
        gl_lds16(gK1 + koff, Ks + 2048 + wave * 512);
        gl_lds16(gV0 + kb * 64, Vt + wave * 512);
        gl_lds16(gV1 + kb * 64, Vt + 2048 + wave * 512);
        float padd[4];
#pragma unroll
        for (int j = 0; j < 4; ++j)
            padd[j] = (1.0f - mrow[kb * 64 + j * 16 + fr]) * (-10000.0f * LOG2E);
        __syncthreads();                               // DMA visible

        // ---- S = Q K^T ----
        f32x4 sacc[4] = {};
#pragma unroll
        for (int j = 0; j < 4; ++j) {
            const int rb = (j * 16 + fr) * 64;
            bf16x8 bk0 = *(const bf16x8*)&Ks[rb + off0];
            bf16x8 bk1 = *(const bf16x8*)&Ks[rb + off1];
            sacc[j] = __builtin_amdgcn_mfma_f32_16x16x32_bf16(aq0, bk0, sacc[j], 0, 0, 0);
            sacc[j] = __builtin_amdgcn_mfma_f32_16x16x32_bf16(aq1, bk1, sacc[j], 0, 0, 0);
        }

        // ---- mask + online softmax (log2 domain) ----
#pragma unroll
        for (int r = 0; r < 4; ++r) {
            int qq = qb * 64 + wave * 16 + quad * 4 + r;
            float v[4];
            float rmax = -1e30f;
#pragma unroll
            for (int j = 0; j < 4; ++j) {
                int kk = kb * 64 + j * 16 + fr;
                float sv = sacc[j][r] * SCALE2 + padd[j];
                v[j] = (kk > qq) ? -1e30f : sv;
                rmax = fmaxf(rmax, v[j]);
            }
#pragma unroll
            for (int m = 8; m; m >>= 1) rmax = fmaxf(rmax, __shfl_xor(rmax, m, 16));
            float mnew = fmaxf(mprev[r], rmax);
            float alpha = exp2f(mprev[r] - mnew);
            float rsum = 0.f;
            ushort pb[4];
#pragma unroll
            for (int j = 0; j < 4; ++j) {
                float p = exp2f(v[j] - mnew);
                rsum += p;
                pb[j] = f2bf(p);
            }
#pragma unroll
            for (int m = 8; m; m >>= 1) rsum += __shfl_xor(rsum, m, 16);
            lsum[r] = lsum[r] * alpha + rsum;
            mprev[r] = mnew;
#pragma unroll
            for (int j = 0; j < 4; ++j) {
                o[j][r] *= alpha;
                Ps[(wave * 16 + quad * 4 + r) * LQP + j * 16 + fr] = pb[j];
            }
        }
        // Ps strip is wave-private: no barrier before re-read.

        // ---- O += P V ----
        bf16x8 pa0 = *(const bf16x8*)&Ps[(wave * 16 + fr) * LQP + quad * 8];
        bf16x8 pa1 = *(const bf16x8*)&Ps[(wave * 16 + fr) * LQP + 32 + quad * 8];
#pragma unroll
        for (int j = 0; j < 4; ++j) {
            const int rb = (j * 16 + fr) * 64;
            bf16x8 bv0 = *(const bf16x8*)&Vt[rb + off0];
            bf16x8 bv1 = *(const bf16x8*)&Vt[rb + off1];
            o[j] = __builtin_amdgcn_mfma_f32_16x16x32_bf16(pa0, bv0, o[j], 0, 0, 0);
            o[j] = __builtin_amdgcn_mfma_f32_16x16x32_bf16(pa1, bv1, o[j], 0, 0, 0);
        }
    }

    // ---- epilogue ----
#pragma unroll
    for (int r = 0; r < 4; ++r) {
        int qq = qb * 64 + wave * 16 + quad * 4 + r;
        float inv = 1.0f / lsum[r];
#pragma unroll
        for (int j = 0; j < 4; ++j)
            O[((size_t)(b * SEQ + qq)) * D + h * HD + j * 16 + fr] = f2bf(o[j][r] * inv);
    }
}

// ---------------------------------------------------------------------------
extern "C" void kernel_launch(void* const* d_in, const int* in_sizes, int n_in,
                              void* d_out, int out_size, void* d_ws, size_t ws_size,
                              hipStream_t stream)
{
    const float* x     = (const float*)d_in[0];
    const float* amask = (const float*)d_in[1];
    const float* Wq    = (const float*)d_in[2];
    const float* bq    = (const float*)d_in[3];
    const float* Wk    = (const float*)d_in[4];
    const float* bk    = (const float*)d_in[5];
    const float* Wv    = (const float*)d_in[6];
    const float* bv    = (const float*)d_in[7];
    const float* Wo    = (const float*)d_in[8];
    const float* bo    = (const float*)d_in[9];
    const float* gamma = (const float*)d_in[10];
    const float* beta  = (const float*)d_in[11];
    float* out = (float*)d_out;

    const size_t MROWS = (size_t)BATCH * SEQ;  // 8192
    const size_t MB = 1024 * 1024;
    char* ws = (char*)d_ws;
    ushort* Qb    = (ushort*)(ws);             // 16 MB bf16
    ushort* Kb    = (ushort*)(ws + 16 * MB);   // 16 MB
    ushort* Vb    = (ushort*)(ws + 32 * MB);   // 16 MB
    ushort* xn_bf = (ushort*)(ws + 48 * MB);   // 16 MB (reused as attn_bf)
    ushort* Vtb   = (ushort*)(ws + 64 * MB);   // 16 MB transposed V
    ushort* Wq_bf = (ushort*)(ws + 80 * MB);   // 2 MB each
    ushort* Wk_bf = (ushort*)(ws + 82 * MB);
    ushort* Wv_bf = (ushort*)(ws + 84 * MB);
    ushort* Wo_bf = (ushort*)(ws + 86 * MB);
    ushort* attn_bf = xn_bf;

    const int WN = D * D;
    cvt_bf16<<<WN / 1024, 256, 0, stream>>>(Wq, Wq_bf, WN);
    cvt_bf16<<<WN / 1024, 256, 0, stream>>>(Wk, Wk_bf, WN);
    cvt_bf16<<<WN / 1024, 256, 0, stream>>>(Wv, Wv_bf, WN);
    cvt_bf16<<<WN / 1024, 256, 0, stream>>>(Wo, Wo_bf, WN);

    ln_kernel<<<dim3((unsigned)MROWS), 256, 0, stream>>>(x, gamma, beta, xn_bf);

    dim3 gg(D / 128, (unsigned)(MROWS / 128));
    gemm_mfma<<<gg, 256, 0, stream>>>(xn_bf, Wq_bf, bq, nullptr, nullptr, Qb, 1, (int)MROWS, D, D);
    gemm_mfma<<<gg, 256, 0, stream>>>(xn_bf, Wk_bf, bk, nullptr, nullptr, Kb, 1, (int)MROWS, D, D);
    gemm_mfma<<<gg, 256, 0, stream>>>(xn_bf, Wv_bf, bv, nullptr, nullptr, Vb, 1, (int)MROWS, D, D);

    vtrans<<<dim3(SEQ / 64, NH, BATCH), 256, 0, stream>>>(Vb, Vtb);

    flash_mfma<<<dim3(SEQ / 64, NH, BATCH), 256, 0, stream>>>(Qb, Kb, Vtb, amask, attn_bf);

    gemm_mfma<<<gg, 256, 0, stream>>>(attn_bf, Wo_bf, bo, x, out, nullptr, 0, (int)MROWS, D, D);
}

// Round 5
// 332.286 us; speedup vs baseline: 8.8360x; 1.5286x over previous
//
#include <hip/hip_runtime.h>

#define D 1024
#define NH 16
#define HD 64
#define SEQ 2048
#define BATCH 4
#define LN_EPS 1e-5f
#define LOG2E 1.44269504088896f

typedef __attribute__((ext_vector_type(8))) __bf16 bf16x8;
typedef __attribute__((ext_vector_type(4))) float f32x4;

__device__ __forceinline__ ushort f2bf(float f) {
    union { float f; uint u; } c; c.f = f;
    uint u = c.u + 0x7fffu + ((c.u >> 16) & 1u);   // RNE
    return (ushort)(u >> 16);
}

// async global->LDS DMA, 16B per lane; LDS dest = wave-uniform base + lane*16
__device__ __forceinline__ void gl_lds16(const ushort* g, ushort* lds) {
    __builtin_amdgcn_global_load_lds(
        (const __attribute__((address_space(1))) void*)g,
        (__attribute__((address_space(3))) void*)lds, 16, 0, 0);
}

// ---------------------------------------------------------------------------
// fp32 -> bf16 bulk convert (weights)
// ---------------------------------------------------------------------------
__global__ __launch_bounds__(256) void cvt_bf16(const float* __restrict__ in,
                                                ushort* __restrict__ out, int n)
{
    int i = (blockIdx.x * 256 + threadIdx.x) * 4;
    if (i < n) {
        float4 v = *(const float4*)(in + i);
        ushort4 o;
        o.x = f2bf(v.x); o.y = f2bf(v.y); o.z = f2bf(v.z); o.w = f2bf(v.w);
        *(ushort4*)(out + i) = o;
    }
}

// ---------------------------------------------------------------------------
// LayerNorm: one block per row, 256 threads x float4; writes bf16
// ---------------------------------------------------------------------------
__global__ __launch_bounds__(256) void ln_kernel(const float* __restrict__ x,
    const float* __restrict__ gamma, const float* __restrict__ beta,
    ushort* __restrict__ xn)
{
    int row = blockIdx.x;
    int tid = threadIdx.x;
    float4 v = ((const float4*)(x + (size_t)row * D))[tid];
    float s = v.x + v.y + v.z + v.w;
#pragma unroll
    for (int off = 32; off > 0; off >>= 1) s += __shfl_down(s, off, 64);
    __shared__ float red1[4], red2[4];
    int wid = tid >> 6, lane = tid & 63;
    if (lane == 0) red1[wid] = s;
    __syncthreads();
    float mean = (red1[0] + red1[1] + red1[2] + red1[3]) * (1.0f / D);
    float dx = v.x - mean, dy = v.y - mean, dz = v.z - mean, dw = v.w - mean;
    float ss = dx * dx + dy * dy + dz * dz + dw * dw;
#pragma unroll
    for (int off = 32; off > 0; off >>= 1) ss += __shfl_down(ss, off, 64);
    if (lane == 0) red2[wid] = ss;
    __syncthreads();
    float var = (red2[0] + red2[1] + red2[2] + red2[3]) * (1.0f / D);
    float rstd = rsqrtf(var + LN_EPS);
    float4 g = ((const float4*)gamma)[tid];
    float4 b = ((const float4*)beta)[tid];
    ushort4 o;
    o.x = f2bf(dx * rstd * g.x + b.x);
    o.y = f2bf(dy * rstd * g.y + b.y);
    o.z = f2bf(dz * rstd * g.z + b.z);
    o.w = f2bf(dw * rstd * g.w + b.w);
    ((ushort4*)(xn + (size_t)row * D))[tid] = o;
}

// ---------------------------------------------------------------------------
// Fused QKV GEMM: W = stacked [Wq;Wk;Wv] = [3072][1024] bf16 (adjacent in ws).
// Grid (24, 64). Region 0->Q, 1->K row-major bf16; region 2 writes V
// directly TRANSPOSED to Vt[b][h][d][s] (scattered b16 stores, L2-coalesced).
// ---------------------------------------------------------------------------
#define BM 128
#define BK 32
__global__ __launch_bounds__(256) void gemm_qkv(
    const ushort* __restrict__ A,    // [M,1024] bf16
    const ushort* __restrict__ W,    // [3072,1024] bf16
    const float* __restrict__ bq, const float* __restrict__ bk,
    const float* __restrict__ bv,
    ushort* __restrict__ Cq, ushort* __restrict__ Ck,
    ushort* __restrict__ CvT,
    int M, int K)
{
    __shared__ ushort As[BM * BK];
    __shared__ ushort Ws[BM * BK];
    const int tid = threadIdx.x;
    const int lane = tid & 63;
    const int wave = tid >> 6;
    const int wr = wave >> 1, wc = wave & 1;
    const int m0 = blockIdx.y * BM;
    const int n0g = blockIdx.x * BM;        // 0..2944 over 3072
    const int region = n0g >> 10;           // 0=Q 1=K 2=V
    const int n0l = n0g & 1023;
    const float* bias = region == 0 ? bq : (region == 1 ? bk : bv);
    const int srow = tid >> 2;
    const int scol = (tid & 3) * 8;
    const int fr = lane & 15, quad = lane >> 4;

    const ushort* gA0 = A + (size_t)(m0 + srow) * K + scol;
    const ushort* gA1 = gA0 + (size_t)64 * K;
    const ushort* gW0 = W + (size_t)(n0g + srow) * K + scol;
    const ushort* gW1 = gW0 + (size_t)64 * K;

    f32x4 acc[4][4] = {};

    for (int k0 = 0; k0 < K; k0 += BK) {
        __syncthreads();
        gl_lds16(gA0 + k0, As + wave * 512);
        gl_lds16(gA1 + k0, As + 2048 + wave * 512);
        gl_lds16(gW0 + k0, Ws + wave * 512);
        gl_lds16(gW1 + k0, Ws + 2048 + wave * 512);
        __syncthreads();
        bf16x8 af[4], bf[4];
#pragma unroll
        for (int i = 0; i < 4; ++i) {
            af[i] = *(const bf16x8*)&As[(wr * 64 + i * 16 + fr) * BK + quad * 8];
            bf[i] = *(const bf16x8*)&Ws[(wc * 64 + i * 16 + fr) * BK + quad * 8];
        }
#pragma unroll
        for (int i = 0; i < 4; ++i)
#pragma unroll
            for (int j = 0; j < 4; ++j)
                acc[i][j] = __builtin_amdgcn_mfma_f32_16x16x32_bf16(af[i], bf[j], acc[i][j], 0, 0, 0);
    }

#pragma unroll
    for (int j = 0; j < 4; ++j) {
        int col = n0l + wc * 64 + j * 16 + fr;      // 0..1023 local
        float bvl = bias[col];
#pragma unroll
        for (int i = 0; i < 4; ++i) {
#pragma unroll
            for (int r = 0; r < 4; ++r) {
                int row = m0 + wr * 64 + i * 16 + quad * 4 + r;
                ushort hv = f2bf(acc[i][j][r] + bvl);
                if (region == 0) {
                    Cq[(size_t)row * 1024 + col] = hv;
                } else if (region == 1) {
                    Ck[(size_t)row * 1024 + col] = hv;
                } else {
                    int bb = row >> 11, s = row & 2047;
                    int hh = col >> 6, d = col & 63;
                    CvT[(((size_t)bb * NH + hh) * HD + d) * SEQ + s] = hv;
                }
            }
        }
    }
}

// ---------------------------------------------------------------------------
// MFMA flash attention, S^T formulation (S^T = K·Q^T so each lane owns one
// q-row: no per-iter shuffles), fixed-max exp2 softmax (scores bounded),
// paired q-tiles (i, 31-i) for uniform 33-iter blocks. Q frags direct from
// global; K & pre-transposed V staged via swizzled global_load_lds.
// ---------------------------------------------------------------------------
#define PSP 72   // Ps pitch (ushorts)
__global__ __launch_bounds__(256) void flash_mfma(
    const ushort* __restrict__ Q, const ushort* __restrict__ K,
    const ushort* __restrict__ VtG, const float* __restrict__ mask,
    ushort* __restrict__ O)
{
    const int bx = blockIdx.x, h = blockIdx.y, b = blockIdx.z;
    __shared__ ushort Ks[64 * 64];   // [key][d], swizzled 16B chunks
    __shared__ ushort Vt[64 * 64];   // [d][key], swizzled 16B chunks
    __shared__ ushort Ps[64 * PSP];  // [q][key], wave-private 16-row strips
    const int tid = threadIdx.x;
    const int lane = tid & 63, wave = tid >> 6;
    const int fr = lane & 15, quad = lane >> 4;
    const int srow = tid >> 3;                    // 0..31
    const int sc8 = tid & 7;
    const int g8 = sc8 ^ (srow & 7);              // swizzled global chunk
    const int swf = fr & 7;

    const ushort* gK0 = K + (size_t)(b * SEQ) * D + h * HD + (size_t)srow * D + g8 * 8;
    const ushort* gK1 = gK0 + (size_t)32 * D;
    const ushort* gV0 = VtG + ((size_t)(b * NH + h) * HD + srow) * SEQ + g8 * 8;
    const ushort* gV1 = gV0 + (size_t)32 * SEQ;
    const float* mrow = mask + (size_t)b * SEQ;
    const float SCALE2 = 0.125f * LOG2E;
    const float MASKC = -10000.0f * LOG2E;

    for (int phase = 0; phase < 2; ++phase) {
        const int qb = phase ? (31 - bx) : bx;
        // Q B-fragments straight from global (once per phase)
        const ushort* qptr = Q + ((size_t)(b * SEQ + qb * 64 + wave * 16 + fr)) * D
                               + h * HD + quad * 8;
        bf16x8 qf0 = *(const bf16x8*)(qptr);
        bf16x8 qf1 = *(const bf16x8*)(qptr + 32);

        f32x4 oacc[4] = {};        // oacc[dt][r]: q=wave*16+quad*4+r, d=dt*16+fr
        float lsum4[4] = {};       // partial sums for q = wave*16+fr

        for (int kb = 0; kb <= qb; ++kb) {
            __syncthreads();                       // prev iter LDS reads done
            gl_lds16(gK0 + (size_t)kb * 64 * D, Ks + wave * 512);
            gl_lds16(gK1 + (size_t)kb * 64 * D, Ks + 2048 + wave * 512);
            gl_lds16(gV0 + kb * 64, Vt + wave * 512);
            gl_lds16(gV1 + kb * 64, Vt + 2048 + wave * 512);
            f32x4 mv[4];
#pragma unroll
            for (int jt = 0; jt < 4; ++jt)
                mv[jt] = ((const f32x4*)(mrow + kb * 64))[jt * 4 + quad];
            __syncthreads();                       // DMA drained + visible

            // ---- S^T = K·Q^T : lane holds q=wave*16+fr, keys jt*16+quad*4+r
            f32x4 sacc[4] = {};
#pragma unroll
            for (int jt = 0; jt < 4; ++jt) {
                const int rb = (jt * 16 + fr) * 64;
                bf16x8 kf0 = *(const bf16x8*)&Ks[rb + ((quad) ^ swf) * 8];
                bf16x8 kf1 = *(const bf16x8*)&Ks[rb + ((4 + quad) ^ swf) * 8];
                sacc[jt] = __builtin_amdgcn_mfma_f32_16x16x32_bf16(kf0, qf0, sacc[jt], 0, 0, 0);
                sacc[jt] = __builtin_amdgcn_mfma_f32_16x16x32_bf16(kf1, qf1, sacc[jt], 0, 0, 0);
            }

            // ---- fixed-max softmax (exp2 domain), truncate-to-bf16 P ----
            const bool diag = (kb == qb);
            const int ql = wave * 16 + fr;
#pragma unroll
            for (int jt = 0; jt < 4; ++jt) {
                float p[4];
#pragma unroll
                for (int r = 0; r < 4; ++r) {
                    float padd = fmaf(mv[jt][r], -MASKC, MASKC);  // (1-m)*-10000*log2e
                    float v = fmaf(sacc[jt][r], SCALE2, padd);
                    if (diag) {
                        int keyl = jt * 16 + quad * 4 + r;
                        v = (keyl > ql) ? -1e30f : v;
                    }
                    float e = exp2f(v);
                    e = __uint_as_float(__float_as_uint(e) & 0xffff0000u);  // bf16-trunc
                    p[r] = e;
                    lsum4[r] += e;                 // denominator from SAME values
                }
                uint lo = (__float_as_uint(p[0]) >> 16) | (__float_as_uint(p[1]) & 0xffff0000u);
                uint hi = (__float_as_uint(p[2]) >> 16) | (__float_as_uint(p[3]) & 0xffff0000u);
                union { uint2 u; ushort4 s; } pu;
                pu.u.x = lo; pu.u.y = hi;
                *(ushort4*)&Ps[(wave * 16 + fr) * PSP + jt * 16 + quad * 4] = pu.s;
            }
            // Ps strip is wave-private: no barrier needed.

            // ---- O = P·V via A=P (LDS), B=Vt rows d ----
            bf16x8 pa0 = *(const bf16x8*)&Ps[(wave * 16 + fr) * PSP + quad * 8];
            bf16x8 pa1 = *(const bf16x8*)&Ps[(wave * 16 + fr) * PSP + 32 + quad * 8];
#pragma unroll
            for (int dt = 0; dt < 4; ++dt) {
                const int rb = (dt * 16 + fr) * 64;
                bf16x8 vf0 = *(const bf16x8*)&Vt[rb + ((quad) ^ swf) * 8];
                bf16x8 vf1 = *(const bf16x8*)&Vt[rb + ((4 + quad) ^ swf) * 8];
                oacc[dt] = __builtin_amdgcn_mfma_f32_16x16x32_bf16(pa0, vf0, oacc[dt], 0, 0, 0);
                oacc[dt] = __builtin_amdgcn_mfma_f32_16x16x32_bf16(pa1, vf1, oacc[dt], 0, 0, 0);
            }
        }

        // ---- finalize: reduce lsum across quads, remap q=fr -> q=quad*4+r ----
        float lt = (lsum4[0] + lsum4[1]) + (lsum4[2] + lsum4[3]);
        lt += __shfl_xor(lt, 16, 64);
        lt += __shfl_xor(lt, 32, 64);
        float linv[4];
#pragma unroll
        for (int r = 0; r < 4; ++r)
            linv[r] = 1.0f / __shfl(lt, quad * 4 + r, 64);
#pragma unroll
        for (int dt = 0; dt < 4; ++dt)
#pragma unroll
            for (int r = 0; r < 4; ++r) {
                int q = qb * 64 + wave * 16 + quad * 4 + r;
                O[((size_t)(b * SEQ + q)) * D + h * HD + dt * 16 + fr] =
                    f2bf(oacc[dt][r] * linv[r]);
            }
    }
}

// ---------------------------------------------------------------------------
// bf16 MFMA GEMM for the output projection (+bias +fp32 residual).
// ---------------------------------------------------------------------------
__global__ __launch_bounds__(256) void gemm_mfma(
    const ushort* __restrict__ A,   // [M,K] bf16
    const ushort* __restrict__ W,   // [N,K] bf16
    const float* __restrict__ bias,
    const float* __restrict__ resid,
    float* __restrict__ Cf,
    int M, int N, int K)
{
    __shared__ ushort As[BM * BK];
    __shared__ ushort Ws[BM * BK];
    const int tid = threadIdx.x;
    const int lane = tid & 63;
    const int wave = tid >> 6;
    const int wr = wave >> 1, wc = wave & 1;
    const int m0 = blockIdx.y * BM, n0 = blockIdx.x * BM;
    const int srow = tid >> 2;
    const int scol = (tid & 3) * 8;
    const int fr = lane & 15, quad = lane >> 4;

    const ushort* gA0 = A + (size_t)(m0 + srow) * K + scol;
    const ushort* gA1 = gA0 + (size_t)64 * K;
    const ushort* gW0 = W + (size_t)(n0 + srow) * K + scol;
    const ushort* gW1 = gW0 + (size_t)64 * K;

    f32x4 acc[4][4] = {};

    for (int k0 = 0; k0 < K; k0 += BK) {
        __syncthreads();
        gl_lds16(gA0 + k0, As + wave * 512);
        gl_lds16(gA1 + k0, As + 2048 + wave * 512);
        gl_lds16(gW0 + k0, Ws + wave * 512);
        gl_lds16(gW1 + k0, Ws + 2048 + wave * 512);
        __syncthreads();
        bf16x8 af[4], bf[4];
#pragma unroll
        for (int i = 0; i < 4; ++i) {
            af[i] = *(const bf16x8*)&As[(wr * 64 + i * 16 + fr) * BK + quad * 8];
            bf[i] = *(const bf16x8*)&Ws[(wc * 64 + i * 16 + fr) * BK + quad * 8];
        }
#pragma unroll
        for (int i = 0; i < 4; ++i)
#pragma unroll
            for (int j = 0; j < 4; ++j)
                acc[i][j] = __builtin_amdgcn_mfma_f32_16x16x32_bf16(af[i], bf[j], acc[i][j], 0, 0, 0);
    }

#pragma unroll
    for (int j = 0; j < 4; ++j) {
        int col = n0 + wc * 64 + j * 16 + fr;
        float bvl = bias[col];
#pragma unroll
        for (int i = 0; i < 4; ++i) {
#pragma unroll
            for (int r = 0; r < 4; ++r) {
                int row = m0 + wr * 64 + i * 16 + quad * 4 + r;
                Cf[(size_t)row * N + col] =
                    acc[i][j][r] + bvl + resid[(size_t)row * N + col];
            }
        }
    }
}

// ---------------------------------------------------------------------------
extern "C" void kernel_launch(void* const* d_in, const int* in_sizes, int n_in,
                              void* d_out, int out_size, void* d_ws, size_t ws_size,
                              hipStream_t stream)
{
    const float* x     = (const float*)d_in[0];
    const float* amask = (const float*)d_in[1];
    const float* Wq    = (const float*)d_in[2];
    const float* bq    = (const float*)d_in[3];
    const float* Wk    = (const float*)d_in[4];
    const float* bk    = (const float*)d_in[5];
    const float* Wv    = (const float*)d_in[6];
    const float* bv    = (const float*)d_in[7];
    const float* Wo    = (const float*)d_in[8];
    const float* bo    = (const float*)d_in[9];
    const float* gamma = (const float*)d_in[10];
    const float* beta  = (const float*)d_in[11];
    float* out = (float*)d_out;

    const size_t MROWS = (size_t)BATCH * SEQ;  // 8192
    const size_t MB = 1024 * 1024;
    char* ws = (char*)d_ws;
    ushort* Qb    = (ushort*)(ws);             // 16 MB bf16 [B,S,D]
    ushort* Kb    = (ushort*)(ws + 16 * MB);   // 16 MB [B,S,D]
    ushort* Vtb   = (ushort*)(ws + 32 * MB);   // 16 MB [B,H,D,S]
    ushort* xn_bf = (ushort*)(ws + 48 * MB);   // 16 MB (reused as attn_bf)
    ushort* Wq_bf = (ushort*)(ws + 64 * MB);   // Wq,Wk,Wv MUST stay adjacent
    ushort* Wk_bf = (ushort*)(ws + 66 * MB);
    ushort* Wv_bf = (ushort*)(ws + 68 * MB);
    ushort* Wo_bf = (ushort*)(ws + 70 * MB);
    ushort* attn_bf = xn_bf;

    const int WN = D * D;
    cvt_bf16<<<WN / 1024, 256, 0, stream>>>(Wq, Wq_bf, WN);
    cvt_bf16<<<WN / 1024, 256, 0, stream>>>(Wk, Wk_bf, WN);
    cvt_bf16<<<WN / 1024, 256, 0, stream>>>(Wv, Wv_bf, WN);
    cvt_bf16<<<WN / 1024, 256, 0, stream>>>(Wo, Wo_bf, WN);

    ln_kernel<<<dim3((unsigned)MROWS), 256, 0, stream>>>(x, gamma, beta, xn_bf);

    gemm_qkv<<<dim3(24, 64), 256, 0, stream>>>(xn_bf, Wq_bf, bq, bk, bv,
                                               Qb, Kb, Vtb, (int)MROWS, D);

    flash_mfma<<<dim3(16, NH, BATCH), 256, 0, stream>>>(Qb, Kb, Vtb, amask, attn_bf);

    gemm_mfma<<<dim3(8, 64), 256, 0, stream>>>(attn_bf, Wo_bf, bo, x, out,
                                               (int)MROWS, D, D);
}

// Round 6
// 316.405 us; speedup vs baseline: 9.2795x; 1.0502x over previous
//
#include <hip/hip_runtime.h>

#define D 1024
#define NH 16
#define HD 64
#define SEQ 2048
#define BATCH 4
#define LN_EPS 1e-5f
#define LOG2E 1.44269504088896f

typedef __attribute__((ext_vector_type(8))) __bf16 bf16x8;
typedef __attribute__((ext_vector_type(4))) float f32x4;

__device__ __forceinline__ ushort f2bf(float f) {
    union { float f; uint u; } c; c.f = f;
    uint u = c.u + 0x7fffu + ((c.u >> 16) & 1u);   // RNE
    return (ushort)(u >> 16);
}

// async global->LDS DMA, 16B per lane; LDS dest = wave-uniform base + lane*16
__device__ __forceinline__ void gl_lds16(const ushort* g, ushort* lds) {
    __builtin_amdgcn_global_load_lds(
        (const __attribute__((address_space(1))) void*)g,
        (__attribute__((address_space(3))) void*)lds, 16, 0, 0);
}

// ---------------------------------------------------------------------------
// fp32 -> bf16 convert, 4 weight matrices in one launch (outputs contiguous)
// ---------------------------------------------------------------------------
__global__ __launch_bounds__(256) void cvt4(const float* __restrict__ w0,
    const float* __restrict__ w1, const float* __restrict__ w2,
    const float* __restrict__ w3, ushort* __restrict__ out, int n)
{
    int sel = blockIdx.y;
    const float* in = sel == 0 ? w0 : (sel == 1 ? w1 : (sel == 2 ? w2 : w3));
    int i = (blockIdx.x * 256 + threadIdx.x) * 4;
    if (i < n) {
        float4 v = *(const float4*)(in + i);
        ushort4 o;
        o.x = f2bf(v.x); o.y = f2bf(v.y); o.z = f2bf(v.z); o.w = f2bf(v.w);
        *(ushort4*)(out + (size_t)sel * n + i) = o;
    }
}

// ---------------------------------------------------------------------------
// LayerNorm: one block per row, 256 threads x float4; writes bf16
// ---------------------------------------------------------------------------
__global__ __launch_bounds__(256) void ln_kernel(const float* __restrict__ x,
    const float* __restrict__ gamma, const float* __restrict__ beta,
    ushort* __restrict__ xn)
{
    int row = blockIdx.x;
    int tid = threadIdx.x;
    float4 v = ((const float4*)(x + (size_t)row * D))[tid];
    float s = v.x + v.y + v.z + v.w;
#pragma unroll
    for (int off = 32; off > 0; off >>= 1) s += __shfl_down(s, off, 64);
    __shared__ float red1[4], red2[4];
    int wid = tid >> 6, lane = tid & 63;
    if (lane == 0) red1[wid] = s;
    __syncthreads();
    float mean = (red1[0] + red1[1] + red1[2] + red1[3]) * (1.0f / D);
    float dx = v.x - mean, dy = v.y - mean, dz = v.z - mean, dw = v.w - mean;
    float ss = dx * dx + dy * dy + dz * dz + dw * dw;
#pragma unroll
    for (int off = 32; off > 0; off >>= 1) ss += __shfl_down(ss, off, 64);
    if (lane == 0) red2[wid] = ss;
    __syncthreads();
    float var = (red2[0] + red2[1] + red2[2] + red2[3]) * (1.0f / D);
    float rstd = rsqrtf(var + LN_EPS);
    float4 g = ((const float4*)gamma)[tid];
    float4 b = ((const float4*)beta)[tid];
    ushort4 o;
    o.x = f2bf(dx * rstd * g.x + b.x);
    o.y = f2bf(dy * rstd * g.y + b.y);
    o.z = f2bf(dz * rstd * g.z + b.z);
    o.w = f2bf(dw * rstd * g.w + b.w);
    ((ushort4*)(xn + (size_t)row * D))[tid] = o;
}

// ---------------------------------------------------------------------------
// Shared GEMM K-loop pieces: 128x128 tile, BK=64, XOR-swizzled DMA staging.
// LDS layout: row pitch 64 ushorts; chunk c8 at LDS col holds global chunk
// c8 ^ (row&7). Fragment reads are conflict-free per 8-lane phase.
// ---------------------------------------------------------------------------
#define BM 128
#define BKK 64

// ---------------------------------------------------------------------------
// Fused QKV GEMM: W = stacked [Wq;Wk;Wv] = [3072][1024] bf16. Grid (24, 64).
// Region 0->Q, 1->K row-major bf16; region 2 -> V transposed to [B,H,D,S].
// ---------------------------------------------------------------------------
__global__ __launch_bounds__(256) void gemm_qkv(
    const ushort* __restrict__ A,    // [M,1024] bf16
    const ushort* __restrict__ W,    // [3072,1024] bf16
    const float* __restrict__ bq, const float* __restrict__ bk,
    const float* __restrict__ bv,
    ushort* __restrict__ Cq, ushort* __restrict__ Ck,
    ushort* __restrict__ CvT,
    int M, int K)
{
    __shared__ ushort As[BM * BKK];   // 16 KB
    __shared__ ushort Ws[BM * BKK];
    const int tid = threadIdx.x;
    const int lane = tid & 63;
    const int wave = tid >> 6;
    const int wr = wave >> 1, wc = wave & 1;
    const int m0 = blockIdx.y * BM;
    const int n0g = blockIdx.x * BM;
    const int region = n0g >> 10;
    const int n0l = n0g & 1023;
    const float* bias = region == 0 ? bq : (region == 1 ? bk : bv);
    const int fr = lane & 15, quad = lane >> 4;
    const int r8 = lane >> 3, c8 = lane & 7;
    const int gc8 = c8 ^ r8;               // swizzled global chunk
    const int swf = fr & 7;

    const ushort* gA = A + (size_t)(m0 + wave * 32 + r8) * K + gc8 * 8;
    const ushort* gW = W + (size_t)(n0g + wave * 32 + r8) * K + gc8 * 8;
    ushort* ldsA = As + (wave * 32) * BKK;
    ushort* ldsW = Ws + (wave * 32) * BKK;

    f32x4 acc[4][4] = {};

    for (int k0 = 0; k0 < K; k0 += BKK) {
        __syncthreads();
#pragma unroll
        for (int t = 0; t < 4; ++t) {
            gl_lds16(gA + (size_t)t * 8 * K + k0, ldsA + t * 8 * BKK);
            gl_lds16(gW + (size_t)t * 8 * K + k0, ldsW + t * 8 * BKK);
        }
        __syncthreads();
#pragma unroll
        for (int kh = 0; kh < 2; ++kh) {
            bf16x8 af[4], bf[4];
            const int co = ((kh * 4 + quad) ^ swf) * 8;
#pragma unroll
            for (int i = 0; i < 4; ++i) {
                af[i] = *(const bf16x8*)&As[(wr * 64 + i * 16 + fr) * BKK + co];
                bf[i] = *(const bf16x8*)&Ws[(wc * 64 + i * 16 + fr) * BKK + co];
            }
#pragma unroll
            for (int i = 0; i < 4; ++i)
#pragma unroll
                for (int j = 0; j < 4; ++j)
                    acc[i][j] = __builtin_amdgcn_mfma_f32_16x16x32_bf16(af[i], bf[j], acc[i][j], 0, 0, 0);
        }
    }

#pragma unroll
    for (int j = 0; j < 4; ++j) {
        int col = n0l + wc * 64 + j * 16 + fr;
        float bvl = bias[col];
#pragma unroll
        for (int i = 0; i < 4; ++i) {
#pragma unroll
            for (int r = 0; r < 4; ++r) {
                int row = m0 + wr * 64 + i * 16 + quad * 4 + r;
                ushort hv = f2bf(acc[i][j][r] + bvl);
                if (region == 0) {
                    Cq[(size_t)row * 1024 + col] = hv;
                } else if (region == 1) {
                    Ck[(size_t)row * 1024 + col] = hv;
                } else {
                    int bb = row >> 11, s = row & 2047;
                    int hh = col >> 6, d = col & 63;
                    CvT[(((size_t)bb * NH + hh) * HD + d) * SEQ + s] = hv;
                }
            }
        }
    }
}

// ---------------------------------------------------------------------------
// Output projection GEMM (+bias +fp32 residual), same BK=64 structure.
// ---------------------------------------------------------------------------
__global__ __launch_bounds__(256) void gemm_out(
    const ushort* __restrict__ A, const ushort* __restrict__ W,
    const float* __restrict__ bias, const float* __restrict__ resid,
    float* __restrict__ Cf, int M, int N, int K)
{
    __shared__ ushort As[BM * BKK];
    __shared__ ushort Ws[BM * BKK];
    const int tid = threadIdx.x;
    const int lane = tid & 63;
    const int wave = tid >> 6;
    const int wr = wave >> 1, wc = wave & 1;
    const int m0 = blockIdx.y * BM, n0 = blockIdx.x * BM;
    const int fr = lane & 15, quad = lane >> 4;
    const int r8 = lane >> 3, c8 = lane & 7;
    const int gc8 = c8 ^ r8;
    const int swf = fr & 7;

    const ushort* gA = A + (size_t)(m0 + wave * 32 + r8) * K + gc8 * 8;
    const ushort* gW = W + (size_t)(n0 + wave * 32 + r8) * K + gc8 * 8;
    ushort* ldsA = As + (wave * 32) * BKK;
    ushort* ldsW = Ws + (wave * 32) * BKK;

    f32x4 acc[4][4] = {};

    for (int k0 = 0; k0 < K; k0 += BKK) {
        __syncthreads();
#pragma unroll
        for (int t = 0; t < 4; ++t) {
            gl_lds16(gA + (size_t)t * 8 * K + k0, ldsA + t * 8 * BKK);
            gl_lds16(gW + (size_t)t * 8 * K + k0, ldsW + t * 8 * BKK);
        }
        __syncthreads();
#pragma unroll
        for (int kh = 0; kh < 2; ++kh) {
            bf16x8 af[4], bf[4];
            const int co = ((kh * 4 + quad) ^ swf) * 8;
#pragma unroll
            for (int i = 0; i < 4; ++i) {
                af[i] = *(const bf16x8*)&As[(wr * 64 + i * 16 + fr) * BKK + co];
                bf[i] = *(const bf16x8*)&Ws[(wc * 64 + i * 16 + fr) * BKK + co];
            }
#pragma unroll
            for (int i = 0; i < 4; ++i)
#pragma unroll
                for (int j = 0; j < 4; ++j)
                    acc[i][j] = __builtin_amdgcn_mfma_f32_16x16x32_bf16(af[i], bf[j], acc[i][j], 0, 0, 0);
        }
    }

#pragma unroll
    for (int j = 0; j < 4; ++j) {
        int col = n0 + wc * 64 + j * 16 + fr;
        float bvl = bias[col];
#pragma unroll
        for (int i = 0; i < 4; ++i) {
#pragma unroll
            for (int r = 0; r < 4; ++r) {
                int row = m0 + wr * 64 + i * 16 + quad * 4 + r;
                Cf[(size_t)row * N + col] =
                    acc[i][j][r] + bvl + resid[(size_t)row * N + col];
            }
        }
    }
}

// ---------------------------------------------------------------------------
// MFMA flash attention, S^T formulation, 128 q-rows per block (2 strips per
// wave -> K/V LDS fragment reads amortized 2x). Fixed-max exp2 softmax,
// zero per-iter shuffles. Pairs (t, 15-t) of 128-row tiles: uniform 34 iters.
// ---------------------------------------------------------------------------
#define PSP 72
__global__ __launch_bounds__(256, 3) void flash_mfma(
    const ushort* __restrict__ Q, const ushort* __restrict__ K,
    const ushort* __restrict__ VtG, const float* __restrict__ mask,
    ushort* __restrict__ O)
{
    const int bx = blockIdx.x, h = blockIdx.y, b = blockIdx.z;
    __shared__ ushort Ks[64 * 64];    // [key][d], swizzled 16B chunks
    __shared__ ushort Vt[64 * 64];    // [d][key], swizzled 16B chunks
    __shared__ ushort Ps[128 * PSP];  // [q][key], wave-private strips
    const int tid = threadIdx.x;
    const int lane = tid & 63, wave = tid >> 6;
    const int fr = lane & 15, quad = lane >> 4;
    const int srow = tid >> 3;
    const int sc8 = tid & 7;
    const int g8 = sc8 ^ (srow & 7);
    const int swf = fr & 7;

    const ushort* gK0 = K + (size_t)(b * SEQ) * D + h * HD + (size_t)srow * D + g8 * 8;
    const ushort* gK1 = gK0 + (size_t)32 * D;
    const ushort* gV0 = VtG + ((size_t)(b * NH + h) * HD + srow) * SEQ + g8 * 8;
    const ushort* gV1 = gV0 + (size_t)32 * SEQ;
    const float* mrow = mask + (size_t)b * SEQ;
    const float SCALE2 = 0.125f * LOG2E;
    const float MASKC = -10000.0f * LOG2E;

    for (int phase = 0; phase < 2; ++phase) {
        const int qt = phase ? (15 - bx) : bx;      // 128-row q tile
        const int q0 = qt * 128;
        // Q B-fragments for both strips, straight from global
        bf16x8 qf[2][2];
#pragma unroll
        for (int s = 0; s < 2; ++s) {
            const ushort* qptr = Q + ((size_t)(b * SEQ + q0 + s * 64 + wave * 16 + fr)) * D
                                   + h * HD + quad * 8;
            qf[s][0] = *(const bf16x8*)(qptr);
            qf[s][1] = *(const bf16x8*)(qptr + 32);
        }

        f32x4 oacc[2][4] = {};
        float lsum[2][4] = {};
        const int nkb = 2 * qt + 2;

        for (int kb = 0; kb < nkb; ++kb) {
            __syncthreads();
            gl_lds16(gK0 + (size_t)kb * 64 * D, Ks + wave * 512);
            gl_lds16(gK1 + (size_t)kb * 64 * D, Ks + 2048 + wave * 512);
            gl_lds16(gV0 + kb * 64, Vt + wave * 512);
            gl_lds16(gV1 + kb * 64, Vt + 2048 + wave * 512);
            f32x4 mv[4];
#pragma unroll
            for (int jt = 0; jt < 4; ++jt)
                mv[jt] = ((const f32x4*)(mrow + kb * 64))[jt * 4 + quad];
            __syncthreads();

            const bool s0act = (kb <= 2 * qt);      // strip0 active (wave-uniform)

            // ---- S^T = K·Q^T for both strips (K frags shared) ----
            f32x4 sacc[2][4] = {};
#pragma unroll
            for (int jt = 0; jt < 4; ++jt) {
                const int rb = (jt * 16 + fr) * 64;
                bf16x8 kf0 = *(const bf16x8*)&Ks[rb + ((quad) ^ swf) * 8];
                bf16x8 kf1 = *(const bf16x8*)&Ks[rb + ((4 + quad) ^ swf) * 8];
                sacc[0][jt] = __builtin_amdgcn_mfma_f32_16x16x32_bf16(kf0, qf[0][0], sacc[0][jt], 0, 0, 0);
                sacc[0][jt] = __builtin_amdgcn_mfma_f32_16x16x32_bf16(kf1, qf[0][1], sacc[0][jt], 0, 0, 0);
                sacc[1][jt] = __builtin_amdgcn_mfma_f32_16x16x32_bf16(kf0, qf[1][0], sacc[1][jt], 0, 0, 0);
                sacc[1][jt] = __builtin_amdgcn_mfma_f32_16x16x32_bf16(kf1, qf[1][1], sacc[1][jt], 0, 0, 0);
            }

            // ---- softmax (fixed-max, exp2, bf16-trunc P) ----
            float padd[4][4];
#pragma unroll
            for (int jt = 0; jt < 4; ++jt)
#pragma unroll
                for (int r = 0; r < 4; ++r)
                    padd[jt][r] = fmaf(mv[jt][r], -MASKC, MASKC);
            const int ql = wave * 16 + fr;
#pragma unroll
            for (int s = 0; s < 2; ++s) {
                if (s == 0 && !s0act) continue;
                const bool diag = (kb == 2 * qt + s);
#pragma unroll
                for (int jt = 0; jt < 4; ++jt) {
                    float p[4];
#pragma unroll
                    for (int r = 0; r < 4; ++r) {
                        float v = fmaf(sacc[s][jt][r], SCALE2, padd[jt][r]);
                        if (diag) {
                            int keyl = jt * 16 + quad * 4 + r;
                            v = (keyl > ql) ? -1e30f : v;
                        }
                        float e = exp2f(v);
                        e = __uint_as_float(__float_as_uint(e) & 0xffff0000u);
                        p[r] = e;
                        lsum[s][r] += e;
                    }
                    uint lo = (__float_as_uint(p[0]) >> 16) | (__float_as_uint(p[1]) & 0xffff0000u);
                    uint hi = (__float_as_uint(p[2]) >> 16) | (__float_as_uint(p[3]) & 0xffff0000u);
                    union { uint2 u; ushort4 us; } pu;
                    pu.u.x = lo; pu.u.y = hi;
                    *(ushort4*)&Ps[(s * 64 + wave * 16 + fr) * PSP + jt * 16 + quad * 4] = pu.us;
                }
            }
            // Ps strips are wave-private: no barrier needed.

            // ---- O += P·V (V frags shared across strips) ----
            bf16x8 pa[2][2];
#pragma unroll
            for (int s = 0; s < 2; ++s) {
                pa[s][0] = *(const bf16x8*)&Ps[(s * 64 + wave * 16 + fr) * PSP + quad * 8];
                pa[s][1] = *(const bf16x8*)&Ps[(s * 64 + wave * 16 + fr) * PSP + 32 + quad * 8];
            }
#pragma unroll
            for (int dt = 0; dt < 4; ++dt) {
                const int rb = (dt * 16 + fr) * 64;
                bf16x8 vf0 = *(const bf16x8*)&Vt[rb + ((quad) ^ swf) * 8];
                bf16x8 vf1 = *(const bf16x8*)&Vt[rb + ((4 + quad) ^ swf) * 8];
                if (s0act) {
                    oacc[0][dt] = __builtin_amdgcn_mfma_f32_16x16x32_bf16(pa[0][0], vf0, oacc[0][dt], 0, 0, 0);
                    oacc[0][dt] = __builtin_amdgcn_mfma_f32_16x16x32_bf16(pa[0][1], vf1, oacc[0][dt], 0, 0, 0);
                }
                oacc[1][dt] = __builtin_amdgcn_mfma_f32_16x16x32_bf16(pa[1][0], vf0, oacc[1][dt], 0, 0, 0);
                oacc[1][dt] = __builtin_amdgcn_mfma_f32_16x16x32_bf16(pa[1][1], vf1, oacc[1][dt], 0, 0, 0);
            }
        }

        // ---- finalize both strips ----
#pragma unroll
        for (int s = 0; s < 2; ++s) {
            float lt = (lsum[s][0] + lsum[s][1]) + (lsum[s][2] + lsum[s][3]);
            lt += __shfl_xor(lt, 16, 64);
            lt += __shfl_xor(lt, 32, 64);
            float linv[4];
#pragma unroll
            for (int r = 0; r < 4; ++r)
                linv[r] = 1.0f / __shfl(lt, quad * 4 + r, 64);
#pragma unroll
            for (int dt = 0; dt < 4; ++dt)
#pragma unroll
                for (int r = 0; r < 4; ++r) {
                    int q = q0 + s * 64 + wave * 16 + quad * 4 + r;
                    O[((size_t)(b * SEQ + q)) * D + h * HD + dt * 16 + fr] =
                        f2bf(oacc[s][dt][r] * linv[r]);
                }
        }
    }
}

// ---------------------------------------------------------------------------
extern "C" void kernel_launch(void* const* d_in, const int* in_sizes, int n_in,
                              void* d_out, int out_size, void* d_ws, size_t ws_size,
                              hipStream_t stream)
{
    const float* x     = (const float*)d_in[0];
    const float* amask = (const float*)d_in[1];
    const float* Wq    = (const float*)d_in[2];
    const float* bq    = (const float*)d_in[3];
    const float* Wk    = (const float*)d_in[4];
    const float* bk    = (const float*)d_in[5];
    const float* Wv    = (const float*)d_in[6];
    const float* bv    = (const float*)d_in[7];
    const float* Wo    = (const float*)d_in[8];
    const float* bo    = (const float*)d_in[9];
    const float* gamma = (const float*)d_in[10];
    const float* beta  = (const float*)d_in[11];
    float* out = (float*)d_out;

    const size_t MROWS = (size_t)BATCH * SEQ;  // 8192
    const size_t MB = 1024 * 1024;
    char* ws = (char*)d_ws;
    ushort* Qb    = (ushort*)(ws);             // 16 MB bf16 [B,S,D]
    ushort* Kb    = (ushort*)(ws + 16 * MB);   // 16 MB [B,S,D]
    ushort* Vtb   = (ushort*)(ws + 32 * MB);   // 16 MB [B,H,D,S]
    ushort* xn_bf = (ushort*)(ws + 48 * MB);   // 16 MB (reused as attn_bf)
    ushort* Wq_bf = (ushort*)(ws + 64 * MB);   // Wq,Wk,Wv,Wo contiguous
    ushort* Wo_bf = (ushort*)(ws + 70 * MB);
    ushort* attn_bf = xn_bf;

    const int WN = D * D;
    cvt4<<<dim3(WN / 1024, 4), 256, 0, stream>>>(Wq, Wk, Wv, Wo, Wq_bf, WN);

    ln_kernel<<<dim3((unsigned)MROWS), 256, 0, stream>>>(x, gamma, beta, xn_bf);

    gemm_qkv<<<dim3(24, 64), 256, 0, stream>>>(xn_bf, Wq_bf, bq, bk, bv,
                                               Qb, Kb, Vtb, (int)MROWS, D);

    flash_mfma<<<dim3(8, NH, BATCH), 256, 0, stream>>>(Qb, Kb, Vtb, amask, attn_bf);

    gemm_out<<<dim3(8, 64), 256, 0, stream>>>(attn_bf, Wo_bf, bo, x, out,
                                              (int)MROWS, D, D);
}